// Round 1
// baseline (3908.459 us; speedup 1.0000x reference)
//
#include <hip/hip_runtime.h>
#include <cstdint>

#define CDIV(a,b) (((a)+(b)-1)/(b))

// =====================================================================
// PointNet++ SSG classifier forward, fp32 baseline (round 0).
// Pipeline: FPS1 -> ballq1 -> [gather -> 3xGEMM -> maxpool] x4 chunks
//           FPS2 -> ballq2 -> [gather -> 3xGEMM -> maxpool] x4 chunks
//           loc GEMMs -> maxpool -> glob GEMVs -> cls GEMV
// ws peak ~119 MB (bufA 34.4MB + bufB 67.1MB + persistents ~17MB).
// =====================================================================

// ---------------------------- FPS ------------------------------------
// One block per batch. dists live in registers (PPT per thread).
// Tie-break: first (smallest) index, matching jnp.argmax.
template<int NPTS, int MOUT, int NTHR>
__global__ __launch_bounds__(NTHR) void fps_kernel(
    const float* __restrict__ pts, int bstride, int cstride,
    int* __restrict__ out_idx)
{
  constexpr int PPT = NPTS / NTHR;
  constexpr int NW  = NTHR / 64;
  const int b = blockIdx.x;
  const int t = threadIdx.x;
  const float* px = pts + (size_t)b * bstride;
  const float* py = px + cstride;
  const float* pz = px + 2 * cstride;
  __shared__ float s_rv[NW];
  __shared__ int   s_ri[NW];
  __shared__ int   s_last;

  float xs[PPT], ys[PPT], zs[PPT], ds[PPT];
#pragma unroll
  for (int j = 0; j < PPT; ++j) {
    int i = t + j * NTHR;
    xs[j] = px[i]; ys[j] = py[i]; zs[j] = pz[i];
    ds[j] = 1e10f;
  }
  if (t == 0) out_idx[(size_t)b * MOUT] = 0;
  int last = 0;
  for (int it = 1; it < MOUT; ++it) {
    // uniform-address loads of the last selected point (L1/L2 hit)
    float lx = px[last], ly = py[last], lz = pz[last];
    float bestv = -1.0f; int besti = 0;
#pragma unroll
    for (int j = 0; j < PPT; ++j) {
      float dx = xs[j] - lx, dy = ys[j] - ly, dz = zs[j] - lz;
      float d  = dx * dx + dy * dy + dz * dz;
      float nd = fminf(ds[j], d);
      ds[j] = nd;
      if (nd > bestv) { bestv = nd; besti = t + j * NTHR; }  // ascending idx scan -> keeps first
    }
#pragma unroll
    for (int off = 32; off > 0; off >>= 1) {
      float ov = __shfl_down(bestv, off);
      int   oi = __shfl_down(besti, off);
      if (ov > bestv || (ov == bestv && oi < besti)) { bestv = ov; besti = oi; }
    }
    if ((t & 63) == 0) { s_rv[t >> 6] = bestv; s_ri[t >> 6] = besti; }
    __syncthreads();
    if (t == 0) {
      float bv = s_rv[0]; int bi = s_ri[0];
#pragma unroll
      for (int w = 1; w < NW; ++w) {
        float v = s_rv[w]; int i2 = s_ri[w];
        if (v > bv || (v == bv && i2 < bi)) { bv = v; bi = i2; }
      }
      s_last = bi;
      out_idx[(size_t)b * MOUT + it] = bi;
    }
    __syncthreads();
    last = s_last;
  }
}

// -------------------- centroid gather (AoS + SoA) ---------------------
__global__ void gatherc_kernel(
    const float* __restrict__ pts, int bstride, int cstride,
    const int* __restrict__ cidx, int M,
    float* __restrict__ aos, float* __restrict__ soa)
{
  const int b = blockIdx.x, t = threadIdx.x;  // blockDim == M
  const int i = cidx[(size_t)b * M + t];
  const float* p = pts + (size_t)b * bstride;
  float x = p[i], y = p[cstride + i], z = p[2 * cstride + i];
  size_t g = (size_t)b * M + t;
  aos[g * 3 + 0] = x; aos[g * 3 + 1] = y; aos[g * 3 + 2] = z;
  soa[(size_t)b * 3 * M + t]         = x;
  soa[(size_t)b * 3 * M + M + t]     = y;
  soa[(size_t)b * 3 * M + 2 * M + t] = z;
}

// --------------------------- ball query -------------------------------
// First-KNB points (index order) with d2 < r2; pad with the first hit.
template<int NPTS, int KNB, int NTHR>
__global__ __launch_bounds__(NTHR) void ballq_kernel(
    const float* __restrict__ pts, int bstride, int cstride,
    const float* __restrict__ cents, int* __restrict__ out,
    int Mc, float r2)
{
  constexpr int NW  = NTHR / 64;
  constexpr int NCH = NPTS / NTHR;
  const int g = blockIdx.x;
  const int b = g / Mc;
  const int t = threadIdx.x;
  const float* px = pts + (size_t)b * bstride;
  const float* py = px + cstride;
  const float* pz = px + 2 * cstride;
  const float cx = cents[g * 3 + 0], cy = cents[g * 3 + 1], cz = cents[g * 3 + 2];
  __shared__ int s_idx[KNB];
  __shared__ int s_wcnt[NW];
  __shared__ int s_base;
  if (t == 0) s_base = 0;
  __syncthreads();
  const int lane = t & 63, wid = t >> 6;
  for (int c = 0; c < NCH; ++c) {
    int i = c * NTHR + t;
    float dx = px[i] - cx, dy = py[i] - cy, dz = pz[i] - cz;
    bool valid = (dx * dx + dy * dy + dz * dz) < r2;
    unsigned long long mask = __ballot(valid);
    if (lane == 0) s_wcnt[wid] = __popcll(mask);
    int rank = __popcll(mask & ((1ull << lane) - 1ull));
    __syncthreads();
    int base = s_base;
    int prefix = 0;
#pragma unroll
    for (int w = 0; w < NW; ++w) prefix += (w < wid) ? s_wcnt[w] : 0;
    int pos = base + prefix + rank;
    if (valid && pos < KNB) s_idx[pos] = i;
    __syncthreads();
    if (t == 0) {
      int tot = 0;
#pragma unroll
      for (int w = 0; w < NW; ++w) tot += s_wcnt[w];
      s_base = base + tot;
    }
    __syncthreads();
    if (s_base >= KNB) break;   // uniform decision
  }
  int total = s_base < KNB ? s_base : KNB;   // >=1 (centroid hits itself)
  int first = s_idx[0];
  for (int q = t; q < KNB; q += NTHR)
    out[(size_t)g * KNB + q] = (q < total) ? s_idx[q] : first;
}

// ------------------------ SA1 group gather ----------------------------
__global__ void gather1_kernel(
    const float* __restrict__ pts, const int* __restrict__ idx1,
    const float* __restrict__ cents, float* __restrict__ A,
    int g0, int nrows)
{
  int r = blockIdx.x * blockDim.x + threadIdx.x;
  if (r >= nrows) return;
  int gl = r >> 5, j = r & 31;
  int gg = g0 + gl;
  int b  = gg >> 9;                 // /512
  int i  = idx1[(size_t)gg * 32 + j];
  const float* px = pts + (size_t)b * 24576;
  float* row = A + (size_t)r * 3;
  row[0] = px[i]         - cents[gg * 3 + 0];
  row[1] = px[8192 + i]  - cents[gg * 3 + 1];
  row[2] = px[16384 + i] - cents[gg * 3 + 2];
}

// ------------------------ SA2 group gather ----------------------------
// row = [rel xyz (3), feats1[point] (128)]  -> 131 cols
__global__ void gather2_kernel(
    const float* __restrict__ nx1_aos, const float* __restrict__ feats1,
    const int* __restrict__ idx2, const float* __restrict__ nx2_aos,
    float* __restrict__ A, int g0)
{
  const int r = blockIdx.x;           // row within chunk
  const int t = threadIdx.x;          // 128 threads
  int gl = r >> 6, j = r & 63;
  int gg = g0 + gl;
  int b  = gg >> 7;                   // /128
  int i  = idx2[(size_t)gg * 64 + j];
  int p  = b * 512 + i;
  float* row = A + (size_t)r * 131;
  row[3 + t] = feats1[(size_t)p * 128 + t];
  if (t < 3) row[t] = nx1_aos[(size_t)p * 3 + t] - nx2_aos[(size_t)gg * 3 + t];
}

// --------------------------- tiled GEMM -------------------------------
// C[M,N] = act(A[M,K] @ W[N,K]^T + bias), BM=128, BK=16, BN in {64,128}
template<int BN, bool RELU>
__global__ __launch_bounds__(256) void gemm_kernel(
    const float* __restrict__ A, const float* __restrict__ W,
    const float* __restrict__ bias, float* __restrict__ C,
    int Mdim, int Ndim, int Kdim)
{
  constexpr int BM = 128, BK = 16;
  constexpr int TN = BN / 16;
  __shared__ float As[BK][BM + 4];
  __shared__ float Ws[BK][BN + 4];
  const int tid = threadIdx.x;
  const int bm = blockIdx.y * BM;
  const int bn = blockIdx.x * BN;
  const int tx = tid & 15;
  const int ty = tid >> 4;
  float acc[8][TN];
#pragma unroll
  for (int i = 0; i < 8; ++i)
#pragma unroll
    for (int j = 0; j < TN; ++j) acc[i][j] = 0.f;

  const int sk = tid & 15;
  const int sr = tid >> 4;
  for (int k0 = 0; k0 < Kdim; k0 += BK) {
    int gk = k0 + sk;
    bool kin = (gk < Kdim);
#pragma unroll
    for (int s = 0; s < BM / 16; ++s) {
      int row = s * 16 + sr;
      int gr = bm + row;
      As[sk][row] = (kin && gr < Mdim) ? A[(size_t)gr * Kdim + gk] : 0.f;
    }
#pragma unroll
    for (int s = 0; s < BN / 16; ++s) {
      int rown = s * 16 + sr;
      int gn = bn + rown;
      Ws[sk][rown] = (kin && gn < Ndim) ? W[(size_t)gn * Kdim + gk] : 0.f;
    }
    __syncthreads();
#pragma unroll
    for (int kk = 0; kk < BK; ++kk) {
      float af[8], wf[TN];
#pragma unroll
      for (int i = 0; i < 8; ++i) af[i] = As[kk][ty * 8 + i];
#pragma unroll
      for (int j = 0; j < TN; ++j) wf[j] = Ws[kk][tx * TN + j];
#pragma unroll
      for (int i = 0; i < 8; ++i)
#pragma unroll
        for (int j = 0; j < TN; ++j)
          acc[i][j] = fmaf(af[i], wf[j], acc[i][j]);
    }
    __syncthreads();
  }
#pragma unroll
  for (int i = 0; i < 8; ++i) {
    int gr = bm + ty * 8 + i;
    if (gr >= Mdim) continue;
#pragma unroll
    for (int j = 0; j < TN; ++j) {
      int gc = bn + tx * TN + j;
      if (gc < Ndim) {
        float v = acc[i][j] + bias[gc];
        if (RELU) v = fmaxf(v, 0.f);
        C[(size_t)gr * Ndim + gc] = v;
      }
    }
  }
}

// --------------------- skinny GEMV (Mdim == 32) -----------------------
template<bool RELU>
__global__ void gemv_kernel(
    const float* __restrict__ A, const float* __restrict__ W,
    const float* __restrict__ bias, float* __restrict__ C,
    int Mdim /* must be 32 */, int Ndim, int Kdim /* %4==0 */)
{
  int o = blockIdx.x * blockDim.x + threadIdx.x;
  if (o >= Mdim * Ndim) return;
  int m = o & 31;
  int n = o >> 5;
  const float4* a4 = (const float4*)(A + (size_t)m * Kdim);
  const float4* w4 = (const float4*)(W + (size_t)n * Kdim);
  float acc = 0.f;
  for (int k = 0; k < (Kdim >> 2); ++k) {
    float4 a = a4[k], w = w4[k];
    acc += a.x * w.x + a.y * w.y + a.z * w.z + a.w * w.w;
  }
  float v = acc + bias[n];
  if (RELU) v = fmaxf(v, 0.f);
  C[(size_t)m * Ndim + n] = v;
}

// ----------------------------- maxpool --------------------------------
// X: [ngroups*rows, C] -> out: [ngroups, C]; blockDim.x == C
__global__ void maxpool_kernel(const float* __restrict__ X,
                               float* __restrict__ out, int rows, int C)
{
  const int g = blockIdx.x, c = threadIdx.x;
  const float* row = X + (size_t)g * rows * C + c;
  float m = row[0];
  for (int r = 1; r < rows; ++r) m = fmaxf(m, row[(size_t)r * C]);
  out[(size_t)g * C + c] = m;
}

// =====================================================================
extern "C" void kernel_launch(void* const* d_in, const int* in_sizes, int n_in,
                              void* d_out, int out_size, void* d_ws, size_t ws_size,
                              hipStream_t stream)
{
  (void)in_sizes; (void)n_in; (void)out_size; (void)ws_size;

  const float* points  = (const float*)d_in[0];
  const float* sa1_w[3] = {(const float*)d_in[1], (const float*)d_in[3], (const float*)d_in[5]};
  const float* sa1_b[3] = {(const float*)d_in[2], (const float*)d_in[4], (const float*)d_in[6]};
  const float* sa2_w[3] = {(const float*)d_in[7], (const float*)d_in[9], (const float*)d_in[11]};
  const float* sa2_b[3] = {(const float*)d_in[8], (const float*)d_in[10], (const float*)d_in[12]};
  const float* loc_w[3] = {(const float*)d_in[13], (const float*)d_in[15], (const float*)d_in[17]};
  const float* loc_b[3] = {(const float*)d_in[14], (const float*)d_in[16], (const float*)d_in[18]};
  const float* glob_w0 = (const float*)d_in[19];
  const float* glob_b0 = (const float*)d_in[20];
  const float* glob_w1 = (const float*)d_in[21];
  const float* glob_b1 = (const float*)d_in[22];
  const float* cls_w   = (const float*)d_in[23];
  const float* cls_b   = (const float*)d_in[24];

  char* base = (char*)d_ws;
  size_t off = 0;
  auto alloc = [&](size_t nbytes) -> void* {
    void* p = base + off;
    off += (nbytes + 255) & ~(size_t)255;
    return p;
  };
  float* nx1_aos = (float*)alloc((size_t)32 * 512 * 3 * 4);
  float* nx1_soa = (float*)alloc((size_t)32 * 512 * 3 * 4);
  int*   cidx1   = (int*)  alloc((size_t)32 * 512 * 4);
  int*   idx1    = (int*)  alloc((size_t)32 * 512 * 32 * 4);
  float* feats1  = (float*)alloc((size_t)32 * 512 * 128 * 4);
  float* nx2_aos = (float*)alloc((size_t)32 * 128 * 3 * 4);
  float* nx2_soa = (float*)alloc((size_t)32 * 128 * 3 * 4);
  int*   cidx2   = (int*)  alloc((size_t)32 * 128 * 4);
  int*   idx2    = (int*)  alloc((size_t)32 * 128 * 64 * 4);
  float* feats2  = (float*)alloc((size_t)32 * 128 * 256 * 4);
  float* pooled  = (float*)alloc((size_t)32 * 1024 * 4);
  float* gbuf1   = (float*)alloc((size_t)32 * 512 * 4);
  float* gbuf2   = (float*)alloc((size_t)32 * 256 * 4);
  float* bufA    = (float*)alloc((size_t)65536 * 131 * 4);   // 34.4 MB
  float* bufB    = (float*)alloc((size_t)131072 * 128 * 4);  // 67.1 MB

  const float r2a = (float)(0.2 * 0.2);  // match XLA f32(0.04) exactly
  const float r2b = (float)(0.4 * 0.4);

  // ---------------- SA1 ----------------
  fps_kernel<8192, 512, 1024><<<32, 1024, 0, stream>>>(points, 24576, 8192, cidx1);
  gatherc_kernel<<<32, 512, 0, stream>>>(points, 24576, 8192, cidx1, 512, nx1_aos, nx1_soa);
  ballq_kernel<8192, 32, 256><<<32 * 512, 256, 0, stream>>>(points, 24576, 8192, nx1_aos, idx1, 512, r2a);

  for (int c = 0; c < 4; ++c) {
    const int g0 = c * 4096;
    const int rows = 4096 * 32;  // 131072
    gather1_kernel<<<CDIV(rows, 256), 256, 0, stream>>>(points, idx1, nx1_aos, bufA, g0, rows);
    gemm_kernel<64, true><<<dim3(1, CDIV(rows, 128)), 256, 0, stream>>>(bufA, sa1_w[0], sa1_b[0], bufB, rows, 64, 3);
    gemm_kernel<64, true><<<dim3(1, CDIV(rows, 128)), 256, 0, stream>>>(bufB, sa1_w[1], sa1_b[1], bufA, rows, 64, 64);
    gemm_kernel<128, true><<<dim3(1, CDIV(rows, 128)), 256, 0, stream>>>(bufA, sa1_w[2], sa1_b[2], bufB, rows, 128, 64);
    maxpool_kernel<<<4096, 128, 0, stream>>>(bufB, feats1 + (size_t)g0 * 128, 32, 128);
  }

  // ---------------- SA2 ----------------
  fps_kernel<512, 128, 512><<<32, 512, 0, stream>>>(nx1_soa, 1536, 512, cidx2);
  gatherc_kernel<<<32, 128, 0, stream>>>(nx1_soa, 1536, 512, cidx2, 128, nx2_aos, nx2_soa);
  ballq_kernel<512, 64, 256><<<32 * 128, 256, 0, stream>>>(nx1_soa, 1536, 512, nx2_aos, idx2, 128, r2b);

  for (int c = 0; c < 4; ++c) {
    const int g0 = c * 1024;
    const int rows = 1024 * 64;  // 65536
    gather2_kernel<<<rows, 128, 0, stream>>>(nx1_aos, feats1, idx2, nx2_aos, bufA, g0);
    gemm_kernel<128, true><<<dim3(1, CDIV(rows, 128)), 256, 0, stream>>>(bufA, sa2_w[0], sa2_b[0], bufB, rows, 128, 131);
    gemm_kernel<128, true><<<dim3(1, CDIV(rows, 128)), 256, 0, stream>>>(bufB, sa2_w[1], sa2_b[1], bufA, rows, 128, 128);
    gemm_kernel<128, true><<<dim3(2, CDIV(rows, 128)), 256, 0, stream>>>(bufA, sa2_w[2], sa2_b[2], bufB, rows, 256, 128);
    maxpool_kernel<<<1024, 256, 0, stream>>>(bufB, feats2 + (size_t)g0 * 256, 64, 256);
  }

  // ---------------- loc MLP + global maxpool ----------------
  gemm_kernel<128, true><<<dim3(2, 32), 256, 0, stream>>>(feats2, loc_w[0], loc_b[0], bufA, 4096, 256, 256);
  gemm_kernel<128, true><<<dim3(4, 32), 256, 0, stream>>>(bufA, loc_w[1], loc_b[1], bufB, 4096, 512, 256);
  gemm_kernel<128, true><<<dim3(8, 32), 256, 0, stream>>>(bufB, loc_w[2], loc_b[2], bufA, 4096, 1024, 512);
  maxpool_kernel<<<32, 1024, 0, stream>>>(bufA, pooled, 128, 1024);

  // ---------------- glob MLP + classifier ----------------
  gemv_kernel<true><<<CDIV(32 * 512, 256), 256, 0, stream>>>(pooled, glob_w0, glob_b0, gbuf1, 32, 512, 1024);
  gemv_kernel<true><<<CDIV(32 * 256, 256), 256, 0, stream>>>(gbuf1, glob_w1, glob_b1, gbuf2, 32, 256, 512);
  gemv_kernel<false><<<CDIV(32 * 40, 256), 256, 0, stream>>>(gbuf2, cls_w, cls_b, (float*)d_out, 32, 40, 256);
}

// Round 2
// 1765.006 us; speedup vs baseline: 2.2144x; 2.2144x over previous
//
#include <hip/hip_runtime.h>
#include <hip/hip_bf16.h>
#include <cstdint>

#define CDIV(a,b) (((a)+(b)-1)/(b))

typedef short s8v __attribute__((ext_vector_type(8)));
typedef float f4v __attribute__((ext_vector_type(4)));

// ---------------------------------------------------------------------
// helpers
// ---------------------------------------------------------------------
__device__ __forceinline__ unsigned short f2bf_bits(float v) {
  __hip_bfloat16 b = __float2bfloat16(v);
  unsigned short u; __builtin_memcpy(&u, &b, 2);
  return u;
}
__device__ __forceinline__ void bsplit(float v, unsigned short& h, unsigned short& l) {
  __hip_bfloat16 hb = __float2bfloat16(v);
  float hf = __bfloat162float(hb);
  unsigned short hu; __builtin_memcpy(&hu, &hb, 2);
  h = hu;
  l = f2bf_bits(v - hf);
}

// async global->LDS, 16B per lane; lds base must be wave-uniform.
__device__ __forceinline__ void gl2lds16(const void* g, void* l, int lane) {
#if __has_builtin(__builtin_amdgcn_global_load_lds)
  __builtin_amdgcn_global_load_lds(
      (const __attribute__((address_space(1))) unsigned int*)g,
      (__attribute__((address_space(3))) unsigned int*)l, 16, 0, 0);
#else
  ((uint4*)l)[lane] = *(const uint4*)g;
#endif
}

// ---------------------------------------------------------------------
// FPS — DPP wave argmax, coords carried, 1 barrier/iter
// ---------------------------------------------------------------------
template<int C>
__device__ __forceinline__ unsigned dpp32(unsigned v) {
  return (unsigned)__builtin_amdgcn_update_dpp((int)v, (int)v, C, 0xF, 0xF, false);
}
template<int C>
__device__ __forceinline__ void red_step(unsigned long long& pk, float& x, float& y, float& z) {
  unsigned lo = dpp32<C>((unsigned)pk);
  unsigned hi = dpp32<C>((unsigned)(pk >> 32));
  unsigned long long p2 = ((unsigned long long)hi << 32) | lo;
  float x2 = __uint_as_float(dpp32<C>(__float_as_uint(x)));
  float y2 = __uint_as_float(dpp32<C>(__float_as_uint(y)));
  float z2 = __uint_as_float(dpp32<C>(__float_as_uint(z)));
  if (p2 > pk) { pk = p2; x = x2; y = y2; z = z2; }
}

template<int NPTS, int MOUT, int NTHR>
__global__ __launch_bounds__(NTHR, 1) void fps_kernel(
    const float* __restrict__ pts, int bstride, int cstride,
    int* __restrict__ out_idx)
{
  constexpr int PPT = NPTS / NTHR;
  constexpr int NW  = NTHR / 64;
  const int b = blockIdx.x, t = threadIdx.x;
  const int lane = t & 63, wid = t >> 6;
  const float* px = pts + (size_t)b * bstride;
  const float* py = px + cstride;
  const float* pz = px + 2 * cstride;
  __shared__ unsigned long long s_wp[2][NW];
  __shared__ float4 s_w4[2][NW];

  float xs[PPT], ys[PPT], zs[PPT], ds[PPT];
#pragma unroll
  for (int j = 0; j < PPT; ++j) {
    int i = t + j * NTHR;
    xs[j] = px[i]; ys[j] = py[i]; zs[j] = pz[i];
    ds[j] = 1e10f;
  }
  if (t == 0) out_idx[(size_t)b * MOUT] = 0;
  float lx = px[0], ly = py[0], lz = pz[0];

  for (int it = 1; it < MOUT; ++it) {
    const int pb = it & 1;
    float bestv = -1.0f; int besti = 0;
    float bx = 0.f, by = 0.f, bz = 0.f;
#pragma unroll
    for (int j = 0; j < PPT; ++j) {
      float dx = xs[j] - lx, dy = ys[j] - ly, dz = zs[j] - lz;
      float d  = dx * dx + dy * dy + dz * dz;
      float nd = fminf(ds[j], d);
      ds[j] = nd;
      if (nd > bestv) { bestv = nd; besti = t + j * NTHR; bx = xs[j]; by = ys[j]; bz = zs[j]; }
    }
    unsigned long long pk =
        ((unsigned long long)__float_as_uint(bestv) << 32) | (unsigned)(~(unsigned)besti);
    red_step<0x111>(pk, bx, by, bz);   // row_shr:1
    red_step<0x112>(pk, bx, by, bz);   // row_shr:2
    red_step<0x114>(pk, bx, by, bz);   // row_shr:4
    red_step<0x118>(pk, bx, by, bz);   // row_shr:8
    red_step<0x142>(pk, bx, by, bz);   // row_bcast:15
    red_step<0x143>(pk, bx, by, bz);   // row_bcast:31  -> lane 63 global
    if (lane == 63) {
      s_wp[pb][wid] = pk;
      s_w4[pb][wid] = make_float4(bx, by, bz, 0.f);
    }
    __syncthreads();
    unsigned long long bp = s_wp[pb][0]; int bw = 0;
#pragma unroll
    for (int w = 1; w < NW; ++w) {
      unsigned long long v = s_wp[pb][w];
      if (v > bp) { bp = v; bw = w; }
    }
    float4 w4 = s_w4[pb][bw];
    lx = w4.x; ly = w4.y; lz = w4.z;
    if (t == 0) out_idx[(size_t)b * MOUT + it] = (int)(~(unsigned)bp);
  }
}

// -------------------- centroid gather (AoS + SoA) ---------------------
__global__ void gatherc_kernel(
    const float* __restrict__ pts, int bstride, int cstride,
    const int* __restrict__ cidx, int M,
    float* __restrict__ aos, float* __restrict__ soa)
{
  const int b = blockIdx.x, t = threadIdx.x;  // blockDim == M
  const int i = cidx[(size_t)b * M + t];
  const float* p = pts + (size_t)b * bstride;
  float x = p[i], y = p[cstride + i], z = p[2 * cstride + i];
  size_t g = (size_t)b * M + t;
  aos[g * 3 + 0] = x; aos[g * 3 + 1] = y; aos[g * 3 + 2] = z;
  soa[(size_t)b * 3 * M + t]         = x;
  soa[(size_t)b * 3 * M + M + t]     = y;
  soa[(size_t)b * 3 * M + 2 * M + t] = z;
}

// --------------------------- ball query -------------------------------
template<int NPTS, int KNB, int NTHR>
__global__ __launch_bounds__(NTHR) void ballq_kernel(
    const float* __restrict__ pts, int bstride, int cstride,
    const float* __restrict__ cents, int* __restrict__ out,
    int Mc, float r2)
{
  constexpr int NW  = NTHR / 64;
  constexpr int NCH = NPTS / NTHR;
  const int g = blockIdx.x;
  const int b = g / Mc;
  const int t = threadIdx.x;
  const float* px = pts + (size_t)b * bstride;
  const float* py = px + cstride;
  const float* pz = px + 2 * cstride;
  const float cx = cents[g * 3 + 0], cy = cents[g * 3 + 1], cz = cents[g * 3 + 2];
  __shared__ int s_idx[KNB];
  __shared__ int s_wcnt[NW];
  __shared__ int s_base;
  if (t == 0) s_base = 0;
  __syncthreads();
  const int lane = t & 63, wid = t >> 6;
  for (int c = 0; c < NCH; ++c) {
    int i = c * NTHR + t;
    float dx = px[i] - cx, dy = py[i] - cy, dz = pz[i] - cz;
    bool valid = (dx * dx + dy * dy + dz * dz) < r2;
    unsigned long long mask = __ballot(valid);
    if (lane == 0) s_wcnt[wid] = __popcll(mask);
    int rank = __popcll(mask & ((1ull << lane) - 1ull));
    __syncthreads();
    int base = s_base;
    int prefix = 0;
#pragma unroll
    for (int w = 0; w < NW; ++w) prefix += (w < wid) ? s_wcnt[w] : 0;
    int pos = base + prefix + rank;
    if (valid && pos < KNB) s_idx[pos] = i;
    __syncthreads();
    if (t == 0) {
      int tot = 0;
#pragma unroll
      for (int w = 0; w < NW; ++w) tot += s_wcnt[w];
      s_base = base + tot;
    }
    __syncthreads();
    if (s_base >= KNB) break;   // uniform decision
  }
  int total = s_base < KNB ? s_base : KNB;
  int first = s_idx[0];
  for (int q = t; q < KNB; q += NTHR)
    out[(size_t)g * KNB + q] = (q < total) ? s_idx[q] : first;
}

// ---------------- gather1 -> bf16 hi/lo planes, width 32 ---------------
__global__ void gather1p_kernel(
    const float* __restrict__ pts, const int* __restrict__ idx1,
    const float* __restrict__ cents,
    unsigned short* __restrict__ Xh, unsigned short* __restrict__ Xl,
    int g0, int nrows)
{
  int r = blockIdx.x * 256 + threadIdx.x;
  if (r >= nrows) return;
  int gl = r >> 5, j = r & 31;
  int gg = g0 + gl;
  int b  = gg >> 9;
  int i  = idx1[(size_t)gg * 32 + j];
  const float* px = pts + (size_t)b * 24576;
  float vx = px[i]         - cents[gg * 3 + 0];
  float vy = px[8192 + i]  - cents[gg * 3 + 1];
  float vz = px[16384 + i] - cents[gg * 3 + 2];
  union { unsigned short us[8]; uint4 v; } ph, pl;
#pragma unroll
  for (int q = 0; q < 8; ++q) { ph.us[q] = 0; pl.us[q] = 0; }
  bsplit(vx, ph.us[0], pl.us[0]);
  bsplit(vy, ph.us[1], pl.us[1]);
  bsplit(vz, ph.us[2], pl.us[2]);
  uint4 zero = make_uint4(0, 0, 0, 0);
  uint4* dh = (uint4*)(Xh + (size_t)r * 32);
  uint4* dl = (uint4*)(Xl + (size_t)r * 32);
  dh[0] = ph.v; dh[1] = zero; dh[2] = zero; dh[3] = zero;
  dl[0] = pl.v; dl[1] = zero; dl[2] = zero; dl[3] = zero;
}

// -------- gather2 -> planes, width 160 (3 xyz + 128 feats + pad) -------
__global__ void gather2p_kernel(
    const float* __restrict__ nx1_aos, const float* __restrict__ feats1,
    const int* __restrict__ idx2, const float* __restrict__ nx2_aos,
    unsigned short* __restrict__ Xh, unsigned short* __restrict__ Xl, int g0)
{
  const int r = blockIdx.x * 4 + threadIdx.y;   // blockDim (64,4)
  int gl = r >> 6, j = r & 63;
  int gg = g0 + gl;
  int b  = gg >> 7;
  int i  = idx2[(size_t)gg * 64 + j];
  int p  = b * 512 + i;
  size_t ro = (size_t)r * 160;
  for (int c = threadIdx.x; c < 160; c += 64) {
    float v;
    if (c >= 3 && c < 131)      v = feats1[(size_t)p * 128 + c - 3];
    else if (c < 3)             v = nx1_aos[(size_t)p * 3 + c] - nx2_aos[(size_t)gg * 3 + c];
    else                        v = 0.f;
    unsigned short h, l; bsplit(v, h, l);
    Xh[ro + c] = h; Xl[ro + c] = l;
  }
}

// ------------- generic fp32 -> hi/lo split with K padding --------------
__global__ void wsplit_kernel(const float* __restrict__ src,
                              unsigned short* __restrict__ h,
                              unsigned short* __restrict__ l,
                              int rows, int K, int KP)
{
  int i = blockIdx.x * 256 + threadIdx.x;
  int tot = rows * KP;
  if (i >= tot) return;
  int r = i / KP, k = i - r * KP;
  float v = (k < K) ? src[(size_t)r * K + k] : 0.f;
  unsigned short hb, lb; bsplit(v, hb, lb);
  h[i] = hb; l[i] = lb;
}

// ---------------------------------------------------------------------
// MFMA GEMM: C[M,N] = relu(A[M,K] @ W[N,K]^T + b), 3-term bf16 split.
// A/W given as hi/lo bf16 planes (row-major, width Kdim, Kdim%32==0).
// POOL=0: write hi/lo planes of C. POOL=32/64/128: fused max-pool over
// groups of POOL rows -> fp32 Cf.
// ---------------------------------------------------------------------
template<int BN, int POOL>
__global__ __launch_bounds__(256, 1) void mfma_gemm(
    const unsigned short* __restrict__ Ah, const unsigned short* __restrict__ Al,
    const unsigned short* __restrict__ Wh, const unsigned short* __restrict__ Wl,
    const float* __restrict__ bias,
    unsigned short* __restrict__ Ch, unsigned short* __restrict__ Cl,
    float* __restrict__ Cf, int Kdim, int Ndim)
{
  constexpr int WTN = BN / 2, NT = WTN / 16;
  __shared__ unsigned short sA[2][128 * 32];
  __shared__ unsigned short sW[2][BN * 32];
  __shared__ float sPool[4][WTN];
  const int tid = threadIdx.x, lane = tid & 63, wid = tid >> 6;
  const int wm = wid & 1, wn = wid >> 1;
  const size_t bm0 = (size_t)blockIdx.y * 128;
  const int bn0 = blockIdx.x * BN;
  const int mn15 = lane & 15, kgrp = lane >> 4;

  f4v acc[4][NT];
#pragma unroll
  for (int a = 0; a < 4; ++a)
#pragma unroll
    for (int b = 0; b < NT; ++b) acc[a][b] = (f4v){0.f, 0.f, 0.f, 0.f};

  const int sc = lane & 3, srl = lane >> 2;

  for (int k0 = 0; k0 < Kdim; k0 += 32) {
    // stage A rows [wid*32, wid*32+32)
#pragma unroll
    for (int hh = 0; hh < 2; ++hh) {
      const int R = wid * 32 + hh * 16;
      const int m = R + srl;
      const int kg = (sc - m - (m >> 2)) & 3;
      const size_t go = (bm0 + m) * (size_t)Kdim + k0 + kg * 8;
      gl2lds16(Ah + go, &sA[0][R * 32], lane);
      gl2lds16(Al + go, &sA[1][R * 32], lane);
    }
    // stage W
    if (BN == 128) {
#pragma unroll
      for (int hh = 0; hh < 2; ++hh) {
        const int R = wid * 32 + hh * 16;
        const int n = R + srl;
        const int kg = (sc - n - (n >> 2)) & 3;
        const size_t go = (size_t)(bn0 + n) * Kdim + k0 + kg * 8;
        gl2lds16(Wh + go, &sW[0][R * 32], lane);
        gl2lds16(Wl + go, &sW[1][R * 32], lane);
      }
    } else {
      const int R = wid * 16;
      const int n = R + srl;
      const int kg = (sc - n - (n >> 2)) & 3;
      const size_t go = (size_t)(bn0 + n) * Kdim + k0 + kg * 8;
      gl2lds16(Wh + go, &sW[0][R * 32], lane);
      gl2lds16(Wl + go, &sW[1][R * 32], lane);
    }
    __syncthreads();   // drains vmcnt -> LDS ready

    s8v af[2][4], bfr[2][NT];
#pragma unroll
    for (int mt = 0; mt < 4; ++mt) {
      const int m = wm * 64 + mt * 16 + mn15;
      const int cc = (kgrp + m + (m >> 2)) & 3;
      af[0][mt] = *(const s8v*)&sA[0][m * 32 + cc * 8];
      af[1][mt] = *(const s8v*)&sA[1][m * 32 + cc * 8];
    }
#pragma unroll
    for (int nt = 0; nt < NT; ++nt) {
      const int n = wn * WTN + nt * 16 + mn15;
      const int cc = (kgrp + n + (n >> 2)) & 3;
      bfr[0][nt] = *(const s8v*)&sW[0][n * 32 + cc * 8];
      bfr[1][nt] = *(const s8v*)&sW[1][n * 32 + cc * 8];
    }
#pragma unroll
    for (int mt = 0; mt < 4; ++mt)
#pragma unroll
      for (int nt = 0; nt < NT; ++nt) {
        acc[mt][nt] = __builtin_amdgcn_mfma_f32_16x16x32_bf16(af[0][mt], bfr[0][nt], acc[mt][nt], 0, 0, 0);
        acc[mt][nt] = __builtin_amdgcn_mfma_f32_16x16x32_bf16(af[0][mt], bfr[1][nt], acc[mt][nt], 0, 0, 0);
        acc[mt][nt] = __builtin_amdgcn_mfma_f32_16x16x32_bf16(af[1][mt], bfr[0][nt], acc[mt][nt], 0, 0, 0);
      }
    __syncthreads();
  }

  float bv[NT];
#pragma unroll
  for (int nt = 0; nt < NT; ++nt) bv[nt] = bias[bn0 + wn * WTN + nt * 16 + mn15];

  if (POOL == 0) {
#pragma unroll
    for (int mt = 0; mt < 4; ++mt)
#pragma unroll
      for (int nt = 0; nt < NT; ++nt) {
        const int n = bn0 + wn * WTN + nt * 16 + mn15;
#pragma unroll
        for (int r = 0; r < 4; ++r) {
          const size_t m = bm0 + wm * 64 + mt * 16 + (lane >> 4) * 4 + r;
          float v = fmaxf(acc[mt][nt][r] + bv[nt], 0.f);
          unsigned short h, l; bsplit(v, h, l);
          Ch[m * Ndim + n] = h;
          Cl[m * Ndim + n] = l;
        }
      }
  } else if (POOL == 32) {
#pragma unroll
    for (int g = 0; g < 2; ++g)
#pragma unroll
      for (int nt = 0; nt < NT; ++nt) {
        float v = -1e30f;
#pragma unroll
        for (int mt = 2 * g; mt < 2 * g + 2; ++mt)
#pragma unroll
          for (int r = 0; r < 4; ++r) v = fmaxf(v, acc[mt][nt][r]);
        v = fmaxf(v + bv[nt], 0.f);
        v = fmaxf(v, __shfl_xor(v, 16, 64));
        v = fmaxf(v, __shfl_xor(v, 32, 64));
        if (lane < 16) {
          const int n = bn0 + wn * WTN + nt * 16 + mn15;
          Cf[(size_t)(bm0 / 32 + wm * 2 + g) * Ndim + n] = v;
        }
      }
  } else if (POOL == 64) {
#pragma unroll
    for (int nt = 0; nt < NT; ++nt) {
      float v = -1e30f;
#pragma unroll
      for (int mt = 0; mt < 4; ++mt)
#pragma unroll
        for (int r = 0; r < 4; ++r) v = fmaxf(v, acc[mt][nt][r]);
      v = fmaxf(v + bv[nt], 0.f);
      v = fmaxf(v, __shfl_xor(v, 16, 64));
      v = fmaxf(v, __shfl_xor(v, 32, 64));
      if (lane < 16) {
        const int n = bn0 + wn * WTN + nt * 16 + mn15;
        Cf[(size_t)(bm0 / 64 + wm) * Ndim + n] = v;
      }
    }
  } else {  // POOL == 128
    float part[NT];
#pragma unroll
    for (int nt = 0; nt < NT; ++nt) {
      float v = -1e30f;
#pragma unroll
      for (int mt = 0; mt < 4; ++mt)
#pragma unroll
        for (int r = 0; r < 4; ++r) v = fmaxf(v, acc[mt][nt][r]);
      v = fmaxf(v + bv[nt], 0.f);
      v = fmaxf(v, __shfl_xor(v, 16, 64));
      v = fmaxf(v, __shfl_xor(v, 32, 64));
      part[nt] = v;
      if (lane < 16) sPool[wid][nt * 16 + mn15] = v;
    }
    __syncthreads();
    if (wm == 0 && lane < 16) {
#pragma unroll
      for (int nt = 0; nt < NT; ++nt) {
        float v = fmaxf(part[nt], sPool[wid + 1][nt * 16 + mn15]);
        const int n = bn0 + wn * WTN + nt * 16 + mn15;
        Cf[(size_t)(bm0 / 128) * Ndim + n] = v;
      }
    }
  }
}

// --------------------- skinny GEMV (Mdim == 32) -----------------------
template<bool RELU>
__global__ void gemv_kernel(
    const float* __restrict__ A, const float* __restrict__ W,
    const float* __restrict__ bias, float* __restrict__ C,
    int Mdim, int Ndim, int Kdim)
{
  int o = blockIdx.x * blockDim.x + threadIdx.x;
  if (o >= Mdim * Ndim) return;
  int m = o & 31;
  int n = o >> 5;
  const float4* a4 = (const float4*)(A + (size_t)m * Kdim);
  const float4* w4 = (const float4*)(W + (size_t)n * Kdim);
  float acc = 0.f;
  for (int k = 0; k < (Kdim >> 2); ++k) {
    float4 a = a4[k], w = w4[k];
    acc += a.x * w.x + a.y * w.y + a.z * w.z + a.w * w.w;
  }
  float v = acc + bias[n];
  if (RELU) v = fmaxf(v, 0.f);
  C[(size_t)m * Ndim + n] = v;
}

// =====================================================================
extern "C" void kernel_launch(void* const* d_in, const int* in_sizes, int n_in,
                              void* d_out, int out_size, void* d_ws, size_t ws_size,
                              hipStream_t stream)
{
  (void)in_sizes; (void)n_in; (void)out_size; (void)ws_size;

  const float* points  = (const float*)d_in[0];
  const float* sa1_w[3] = {(const float*)d_in[1], (const float*)d_in[3], (const float*)d_in[5]};
  const float* sa1_b[3] = {(const float*)d_in[2], (const float*)d_in[4], (const float*)d_in[6]};
  const float* sa2_w[3] = {(const float*)d_in[7], (const float*)d_in[9], (const float*)d_in[11]};
  const float* sa2_b[3] = {(const float*)d_in[8], (const float*)d_in[10], (const float*)d_in[12]};
  const float* loc_w[3] = {(const float*)d_in[13], (const float*)d_in[15], (const float*)d_in[17]};
  const float* loc_b[3] = {(const float*)d_in[14], (const float*)d_in[16], (const float*)d_in[18]};
  const float* glob_w0 = (const float*)d_in[19];
  const float* glob_b0 = (const float*)d_in[20];
  const float* glob_w1 = (const float*)d_in[21];
  const float* glob_b1 = (const float*)d_in[22];
  const float* cls_w   = (const float*)d_in[23];
  const float* cls_b   = (const float*)d_in[24];

  char* base = (char*)d_ws;
  size_t off = 0;
  auto alloc = [&](size_t nbytes) -> void* {
    void* p = base + off;
    off += (nbytes + 255) & ~(size_t)255;
    return p;
  };

  // plane ping-pong buffers (bf16 bits as ushort)
  const size_t XE = (size_t)65536 * 160;   // max X elems
  const size_t YE = (size_t)131072 * 64;   // max Y elems (== 65536*128)
  unsigned short* Xh = (unsigned short*)alloc(XE * 2);
  unsigned short* Xl = (unsigned short*)alloc(XE * 2);
  unsigned short* Yh = (unsigned short*)alloc(YE * 2);
  unsigned short* Yl = (unsigned short*)alloc(YE * 2);

  // weight planes (9 segments, padded K)
  const int  wrows[9] = {64, 64, 128, 128, 128, 256, 256, 512, 1024};
  const int  wK[9]    = {3, 64, 64, 131, 128, 128, 256, 256, 512};
  const int  wKP[9]   = {32, 64, 64, 160, 128, 128, 256, 256, 512};
  const float* wsrc[9] = {sa1_w[0], sa1_w[1], sa1_w[2],
                          sa2_w[0], sa2_w[1], sa2_w[2],
                          loc_w[0], loc_w[1], loc_w[2]};
  unsigned short *wph[9], *wpl[9];
  for (int s = 0; s < 9; ++s) {
    size_t e = (size_t)wrows[s] * wKP[s];
    wph[s] = (unsigned short*)alloc(e * 2);
    wpl[s] = (unsigned short*)alloc(e * 2);
  }

  float* nx1_aos = (float*)alloc((size_t)32 * 512 * 3 * 4);
  float* nx1_soa = (float*)alloc((size_t)32 * 512 * 3 * 4);
  int*   cidx1   = (int*)  alloc((size_t)32 * 512 * 4);
  int*   idx1    = (int*)  alloc((size_t)32 * 512 * 32 * 4);
  float* feats1  = (float*)alloc((size_t)32 * 512 * 128 * 4);
  float* nx2_aos = (float*)alloc((size_t)32 * 128 * 3 * 4);
  float* nx2_soa = (float*)alloc((size_t)32 * 128 * 3 * 4);
  int*   cidx2   = (int*)  alloc((size_t)32 * 128 * 4);
  int*   idx2    = (int*)  alloc((size_t)32 * 128 * 64 * 4);
  float* feats2  = (float*)alloc((size_t)32 * 128 * 256 * 4);
  float* pooled  = (float*)alloc((size_t)32 * 1024 * 4);
  float* gbuf1   = (float*)alloc((size_t)32 * 512 * 4);
  float* gbuf2   = (float*)alloc((size_t)32 * 256 * 4);

  const float r2a = (float)(0.2 * 0.2);
  const float r2b = (float)(0.4 * 0.4);

  // ---- weight plane conversion ----
  for (int s = 0; s < 9; ++s) {
    int tot = wrows[s] * wKP[s];
    wsplit_kernel<<<CDIV(tot, 256), 256, 0, stream>>>(wsrc[s], wph[s], wpl[s], wrows[s], wK[s], wKP[s]);
  }

  // ---------------- SA1 ----------------
  fps_kernel<8192, 512, 256><<<32, 256, 0, stream>>>(points, 24576, 8192, cidx1);
  gatherc_kernel<<<32, 512, 0, stream>>>(points, 24576, 8192, cidx1, 512, nx1_aos, nx1_soa);
  ballq_kernel<8192, 32, 256><<<32 * 512, 256, 0, stream>>>(points, 24576, 8192, nx1_aos, idx1, 512, r2a);

  for (int c = 0; c < 4; ++c) {
    const int g0 = c * 4096;
    const int rows = 4096 * 32;  // 131072
    gather1p_kernel<<<CDIV(rows, 256), 256, 0, stream>>>(points, idx1, nx1_aos, Xh, Xl, g0, rows);
    mfma_gemm<64, 0><<<dim3(1, rows / 128), 256, 0, stream>>>(
        Xh, Xl, wph[0], wpl[0], sa1_b[0], Yh, Yl, nullptr, 32, 64);
    mfma_gemm<64, 0><<<dim3(1, rows / 128), 256, 0, stream>>>(
        Yh, Yl, wph[1], wpl[1], sa1_b[1], Xh, Xl, nullptr, 64, 64);
    mfma_gemm<128, 32><<<dim3(1, rows / 128), 256, 0, stream>>>(
        Xh, Xl, wph[2], wpl[2], sa1_b[2], nullptr, nullptr,
        feats1 + (size_t)g0 * 128, 64, 128);
  }

  // ---------------- SA2 ----------------
  fps_kernel<512, 128, 256><<<32, 256, 0, stream>>>(nx1_soa, 1536, 512, cidx2);
  gatherc_kernel<<<32, 128, 0, stream>>>(nx1_soa, 1536, 512, cidx2, 128, nx2_aos, nx2_soa);
  ballq_kernel<512, 64, 256><<<32 * 128, 256, 0, stream>>>(nx1_soa, 1536, 512, nx2_aos, idx2, 128, r2b);

  for (int c = 0; c < 4; ++c) {
    const int g0 = c * 1024;
    const int rows = 1024 * 64;  // 65536
    gather2p_kernel<<<dim3(rows / 4), dim3(64, 4), 0, stream>>>(nx1_aos, feats1, idx2, nx2_aos, Xh, Xl, g0);
    mfma_gemm<128, 0><<<dim3(1, rows / 128), 256, 0, stream>>>(
        Xh, Xl, wph[3], wpl[3], sa2_b[0], Yh, Yl, nullptr, 160, 128);
    mfma_gemm<128, 0><<<dim3(1, rows / 128), 256, 0, stream>>>(
        Yh, Yl, wph[4], wpl[4], sa2_b[1], Xh, Xl, nullptr, 128, 128);
    mfma_gemm<128, 64><<<dim3(2, rows / 128), 256, 0, stream>>>(
        Xh, Xl, wph[5], wpl[5], sa2_b[2], nullptr, nullptr,
        feats2 + (size_t)g0 * 256, 128, 256);
  }

  // ---------------- loc MLP (fused global maxpool at L3) ----------------
  wsplit_kernel<<<CDIV(4096 * 256, 256), 256, 0, stream>>>(feats2, Xh, Xl, 4096, 256, 256);
  mfma_gemm<128, 0><<<dim3(2, 32), 256, 0, stream>>>(
      Xh, Xl, wph[6], wpl[6], loc_b[0], Yh, Yl, nullptr, 256, 256);
  mfma_gemm<128, 0><<<dim3(4, 32), 256, 0, stream>>>(
      Yh, Yl, wph[7], wpl[7], loc_b[1], Xh, Xl, nullptr, 256, 512);
  mfma_gemm<128, 128><<<dim3(8, 32), 256, 0, stream>>>(
      Xh, Xl, wph[8], wpl[8], loc_b[2], nullptr, nullptr, pooled, 512, 1024);

  // ---------------- glob MLP + classifier ----------------
  gemv_kernel<true><<<CDIV(32 * 512, 256), 256, 0, stream>>>(pooled, glob_w0, glob_b0, gbuf1, 32, 512, 1024);
  gemv_kernel<true><<<CDIV(32 * 256, 256), 256, 0, stream>>>(gbuf1, glob_w1, glob_b1, gbuf2, 32, 256, 512);
  gemv_kernel<false><<<CDIV(32 * 40, 256), 256, 0, stream>>>(gbuf2, cls_w, cls_b, (float*)d_out, 32, 40, 256);
}

// Round 3
// 1482.237 us; speedup vs baseline: 2.6369x; 1.1908x over previous
//
#include <hip/hip_runtime.h>
#include <hip/hip_bf16.h>
#include <cstdint>

#define CDIV(a,b) (((a)+(b)-1)/(b))

typedef short s8v __attribute__((ext_vector_type(8)));
typedef float f4v __attribute__((ext_vector_type(4)));

// ---------------------------------------------------------------------
// helpers
// ---------------------------------------------------------------------
__device__ __forceinline__ unsigned short f2bf_bits(float v) {
  __hip_bfloat16 b = __float2bfloat16(v);
  unsigned short u; __builtin_memcpy(&u, &b, 2);
  return u;
}
__device__ __forceinline__ void bsplit(float v, unsigned short& h, unsigned short& l) {
  __hip_bfloat16 hb = __float2bfloat16(v);
  float hf = __bfloat162float(hb);
  unsigned short hu; __builtin_memcpy(&hu, &hb, 2);
  h = hu;
  l = f2bf_bits(v - hf);
}

// async global->LDS, 16B per lane; lds base must be wave-uniform.
__device__ __forceinline__ void gl2lds16(const void* g, void* l, int lane) {
#if __has_builtin(__builtin_amdgcn_global_load_lds)
  __builtin_amdgcn_global_load_lds(
      (const __attribute__((address_space(1))) unsigned int*)g,
      (__attribute__((address_space(3))) unsigned int*)l, 16, 0, 0);
#else
  ((uint4*)l)[lane] = *(const uint4*)g;
#endif
}

// ---------------------------------------------------------------------
// FPS — DPP wave argmax, coords carried, 1 barrier/iter, register
// tournament for the cross-wave pick. NTHR sized so per-thread point
// arrays stay register-resident (PPT*4 + ~70 misc < 256 VGPR).
// ---------------------------------------------------------------------
template<int C>
__device__ __forceinline__ unsigned dpp32(unsigned v) {
  return (unsigned)__builtin_amdgcn_update_dpp((int)v, (int)v, C, 0xF, 0xF, false);
}
template<int C>
__device__ __forceinline__ void red_step(unsigned long long& pk, float& x, float& y, float& z) {
  unsigned lo = dpp32<C>((unsigned)pk);
  unsigned hi = dpp32<C>((unsigned)(pk >> 32));
  unsigned long long p2 = ((unsigned long long)hi << 32) | lo;
  float x2 = __uint_as_float(dpp32<C>(__float_as_uint(x)));
  float y2 = __uint_as_float(dpp32<C>(__float_as_uint(y)));
  float z2 = __uint_as_float(dpp32<C>(__float_as_uint(z)));
  if (p2 > pk) { pk = p2; x = x2; y = y2; z = z2; }
}

template<int NPTS, int MOUT, int NTHR>
__global__ __launch_bounds__(NTHR, 1) void fps_kernel(
    const float* __restrict__ pts, int bstride, int cstride,
    int* __restrict__ out_idx)
{
  constexpr int PPT = NPTS / NTHR;
  constexpr int NW  = NTHR / 64;
  const int b = blockIdx.x, t = threadIdx.x;
  const int lane = t & 63, wid = t >> 6;
  const float* px = pts + (size_t)b * bstride;
  const float* py = px + cstride;
  const float* pz = px + 2 * cstride;
  __shared__ unsigned long long s_key[2][NW];
  __shared__ float4 s_c4[2][NW];

  float xs[PPT], ys[PPT], zs[PPT], ds[PPT];
#pragma unroll
  for (int j = 0; j < PPT; ++j) {
    int i = t + j * NTHR;
    xs[j] = px[i]; ys[j] = py[i]; zs[j] = pz[i];
    ds[j] = 1e10f;
  }
  if (t == 0) out_idx[(size_t)b * MOUT] = 0;
  float lx = px[0], ly = py[0], lz = pz[0];

  for (int it = 1; it < MOUT; ++it) {
    const int pb = it & 1;
    float bestv = -1.0f; int besti = 0;
    float bx = 0.f, by = 0.f, bz = 0.f;
#pragma unroll
    for (int j = 0; j < PPT; ++j) {
      float dx = xs[j] - lx, dy = ys[j] - ly, dz = zs[j] - lz;
      float d  = dx * dx + dy * dy + dz * dz;
      float nd = fminf(ds[j], d);
      ds[j] = nd;
      if (nd > bestv) { bestv = nd; besti = t + j * NTHR; bx = xs[j]; by = ys[j]; bz = zs[j]; }
    }
    unsigned long long pk =
        ((unsigned long long)__float_as_uint(bestv) << 32) | (unsigned)(~(unsigned)besti);
    red_step<0x111>(pk, bx, by, bz);   // row_shr:1
    red_step<0x112>(pk, bx, by, bz);   // row_shr:2
    red_step<0x114>(pk, bx, by, bz);   // row_shr:4
    red_step<0x118>(pk, bx, by, bz);   // row_shr:8
    red_step<0x142>(pk, bx, by, bz);   // row_bcast:15
    red_step<0x143>(pk, bx, by, bz);   // row_bcast:31 -> lane 63 has wave winner
    if (lane == 63) {
      s_key[pb][wid] = pk;
      s_c4[pb][wid] = make_float4(bx, by, bz, 0.f);
    }
    __syncthreads();
    // register tournament over NW wave winners (broadcast LDS reads)
    unsigned long long k[NW]; float4 c[NW];
#pragma unroll
    for (int w = 0; w < NW; ++w) { k[w] = s_key[pb][w]; c[w] = s_c4[pb][w]; }
#pragma unroll
    for (int s = NW / 2; s >= 1; s >>= 1)
#pragma unroll
      for (int w = 0; w < s; ++w)
        if (k[w + s] > k[w]) { k[w] = k[w + s]; c[w] = c[w + s]; }
    lx = c[0].x; ly = c[0].y; lz = c[0].z;
    if (t == 0) out_idx[(size_t)b * MOUT + it] = (int)(~(unsigned)k[0]);
  }
}

// -------------------- centroid gather (AoS + SoA) ---------------------
__global__ void gatherc_kernel(
    const float* __restrict__ pts, int bstride, int cstride,
    const int* __restrict__ cidx, int M,
    float* __restrict__ aos, float* __restrict__ soa)
{
  const int b = blockIdx.x, t = threadIdx.x;  // blockDim == M
  const int i = cidx[(size_t)b * M + t];
  const float* p = pts + (size_t)b * bstride;
  float x = p[i], y = p[cstride + i], z = p[2 * cstride + i];
  size_t g = (size_t)b * M + t;
  aos[g * 3 + 0] = x; aos[g * 3 + 1] = y; aos[g * 3 + 2] = z;
  soa[(size_t)b * 3 * M + t]         = x;
  soa[(size_t)b * 3 * M + M + t]     = y;
  soa[(size_t)b * 3 * M + 2 * M + t] = z;
}

// ---------------- ball query — one wave per centroid ------------------
// No barriers: ballot + scalar base carried in-wave; early exit uniform.
template<int NPTS, int KNB, int MC>
__global__ __launch_bounds__(64) void ballq_wave(
    const float* __restrict__ pts, int bstride, int cstride,
    const float* __restrict__ cents, int* __restrict__ out, float r2)
{
  const int g = blockIdx.x;
  const int b = g / MC;
  const int lane = threadIdx.x;
  const float* px = pts + (size_t)b * bstride;
  const float* py = px + cstride;
  const float* pz = px + 2 * cstride;
  const float cx = cents[g * 3 + 0], cy = cents[g * 3 + 1], cz = cents[g * 3 + 2];
  __shared__ int s_idx[KNB];
  int base = 0;
  for (int c = 0; c < NPTS / 64; ++c) {
    int i = c * 64 + lane;
    float dx = px[i] - cx, dy = py[i] - cy, dz = pz[i] - cz;
    bool valid = (dx * dx + dy * dy + dz * dz) < r2;
    unsigned long long mask = __ballot(valid);
    int rank = __popcll(mask & ((1ull << lane) - 1ull));
    int pos = base + rank;
    if (valid && pos < KNB) s_idx[pos] = i;
    base += __popcll(mask);
    if (base >= KNB) break;   // wave-uniform
  }
  int total = base < KNB ? base : KNB;   // >=1 (centroid hits itself)
  int first = s_idx[0];
  if (lane < KNB)
    out[(size_t)g * KNB + lane] = (lane < total) ? s_idx[lane] : first;
}

// ----------- fused SA1 gather + layer1 (K=3, exact fp32 VALU) ----------
// 4 threads per output row; each computes 16 of 64 outputs.
__global__ __launch_bounds__(256) void sa1l1_kernel(
    const float* __restrict__ pts, const int* __restrict__ idx1,
    const float* __restrict__ cents,
    const float* __restrict__ w0, const float* __restrict__ b0,
    unsigned short* __restrict__ Yh, unsigned short* __restrict__ Yl,
    int g0, int nrows)
{
  __shared__ float sw[192];
  __shared__ float sb[64];
  const int tid = threadIdx.x;
  if (tid < 192) sw[tid] = w0[tid];
  else sb[tid - 192] = b0[tid - 192];
  __syncthreads();
  const int r = blockIdx.x * 64 + (tid >> 2);
  if (r >= nrows) return;
  const int q = tid & 3;
  const int gl = r >> 5, j = r & 31, gg = g0 + gl, b = gg >> 9;
  const int i = idx1[(size_t)gg * 32 + j];
  const float* px = pts + (size_t)b * 24576;
  const float x = px[i]         - cents[gg * 3 + 0];
  const float y = px[8192 + i]  - cents[gg * 3 + 1];
  const float z = px[16384 + i] - cents[gg * 3 + 2];
  union { unsigned short us[16]; uint4 v[2]; } ph, pl;
#pragma unroll
  for (int u = 0; u < 16; ++u) {
    const int o = q * 16 + u;
    float v = sw[o * 3] * x + sw[o * 3 + 1] * y + sw[o * 3 + 2] * z + sb[o];
    v = fmaxf(v, 0.f);
    bsplit(v, ph.us[u], pl.us[u]);
  }
  uint4* dh = (uint4*)(Yh + (size_t)r * 64 + q * 16);
  uint4* dl = (uint4*)(Yl + (size_t)r * 64 + q * 16);
  dh[0] = ph.v[0]; dh[1] = ph.v[1];
  dl[0] = pl.v[0]; dl[1] = pl.v[1];
}

// -------- gather2 -> planes, width 160 (3 xyz + 128 feats + pad) -------
// feats1 already stored as bf16 hi/lo planes -> pure permutation copy.
__global__ void gather2p_kernel(
    const float* __restrict__ nx1_aos,
    const unsigned short* __restrict__ f1h, const unsigned short* __restrict__ f1l,
    const int* __restrict__ idx2, const float* __restrict__ nx2_aos,
    unsigned short* __restrict__ Xh, unsigned short* __restrict__ Xl, int g0)
{
  const int r = blockIdx.x * 4 + threadIdx.y;   // blockDim (64,4)
  int gl = r >> 6, j = r & 63;
  int gg = g0 + gl;
  int b  = gg >> 7;
  int i  = idx2[(size_t)gg * 64 + j];
  int p  = b * 512 + i;
  size_t ro = (size_t)r * 160;
  for (int c = threadIdx.x; c < 160; c += 64) {
    unsigned short h, l;
    if (c >= 3 && c < 131) {
      h = f1h[(size_t)p * 128 + c - 3];
      l = f1l[(size_t)p * 128 + c - 3];
    } else if (c < 3) {
      bsplit(nx1_aos[(size_t)p * 3 + c] - nx2_aos[(size_t)gg * 3 + c], h, l);
    } else { h = 0; l = 0; }
    Xh[ro + c] = h; Xl[ro + c] = l;
  }
}

// ------------- all weight fp32 -> hi/lo splits in ONE launch -----------
struct WSplitArgs {
  const float* src[9];
  unsigned short* h[9];
  unsigned short* l[9];
  int K[9];
  int KP[9];
  int cum[10];
};
__global__ void wsplit_all(WSplitArgs a) {
  int i = blockIdx.x * 256 + threadIdx.x;
  if (i >= a.cum[9]) return;
  int s = 0;
#pragma unroll
  for (int t = 1; t < 9; ++t) s += (i >= a.cum[t]);
  int local = i - a.cum[s];
  int KP = a.KP[s], K = a.K[s];
  int r = local / KP, k = local - r * KP;
  float v = (k < K) ? a.src[s][(size_t)r * K + k] : 0.f;
  unsigned short hb, lb; bsplit(v, hb, lb);
  a.h[s][local] = hb; a.l[s][local] = lb;
}

// ---------------------------------------------------------------------
// MFMA GEMM: C[M,N] = relu(A[M,K] @ W[N,K]^T + b), 3-term bf16 split.
// POOL=0: write hi/lo planes Ch/Cl. POOL=32/64/128: fused row max-pool;
// optional fp32 Cf and/or hi/lo pooled planes Chp/Clp.
// ---------------------------------------------------------------------
template<int BN, int POOL>
__global__ __launch_bounds__(256, 1) void mfma_gemm(
    const unsigned short* __restrict__ Ah, const unsigned short* __restrict__ Al,
    const unsigned short* __restrict__ Wh, const unsigned short* __restrict__ Wl,
    const float* __restrict__ bias,
    unsigned short* __restrict__ Ch, unsigned short* __restrict__ Cl,
    float* __restrict__ Cf,
    unsigned short* __restrict__ Chp, unsigned short* __restrict__ Clp,
    int Kdim, int Ndim)
{
  constexpr int WTN = BN / 2, NT = WTN / 16;
  __shared__ unsigned short sA[2][128 * 32];
  __shared__ unsigned short sW[2][BN * 32];
  __shared__ float sPool[4][WTN];
  const int tid = threadIdx.x, lane = tid & 63, wid = tid >> 6;
  const int wm = wid & 1, wn = wid >> 1;
  const size_t bm0 = (size_t)blockIdx.y * 128;
  const int bn0 = blockIdx.x * BN;
  const int mn15 = lane & 15, kgrp = lane >> 4;

  f4v acc[4][NT];
#pragma unroll
  for (int a = 0; a < 4; ++a)
#pragma unroll
    for (int b = 0; b < NT; ++b) acc[a][b] = (f4v){0.f, 0.f, 0.f, 0.f};

  const int sc = lane & 3, srl = lane >> 2;

  for (int k0 = 0; k0 < Kdim; k0 += 32) {
#pragma unroll
    for (int hh = 0; hh < 2; ++hh) {
      const int R = wid * 32 + hh * 16;
      const int m = R + srl;
      const int kg = (sc - m - (m >> 2)) & 3;
      const size_t go = (bm0 + m) * (size_t)Kdim + k0 + kg * 8;
      gl2lds16(Ah + go, &sA[0][R * 32], lane);
      gl2lds16(Al + go, &sA[1][R * 32], lane);
    }
    if (BN == 128) {
#pragma unroll
      for (int hh = 0; hh < 2; ++hh) {
        const int R = wid * 32 + hh * 16;
        const int n = R + srl;
        const int kg = (sc - n - (n >> 2)) & 3;
        const size_t go = (size_t)(bn0 + n) * Kdim + k0 + kg * 8;
        gl2lds16(Wh + go, &sW[0][R * 32], lane);
        gl2lds16(Wl + go, &sW[1][R * 32], lane);
      }
    } else {
      const int R = wid * 16;
      const int n = R + srl;
      const int kg = (sc - n - (n >> 2)) & 3;
      const size_t go = (size_t)(bn0 + n) * Kdim + k0 + kg * 8;
      gl2lds16(Wh + go, &sW[0][R * 32], lane);
      gl2lds16(Wl + go, &sW[1][R * 32], lane);
    }
    __syncthreads();

    s8v af[2][4], bfr[2][NT];
#pragma unroll
    for (int mt = 0; mt < 4; ++mt) {
      const int m = wm * 64 + mt * 16 + mn15;
      const int cc = (kgrp + m + (m >> 2)) & 3;
      af[0][mt] = *(const s8v*)&sA[0][m * 32 + cc * 8];
      af[1][mt] = *(const s8v*)&sA[1][m * 32 + cc * 8];
    }
#pragma unroll
    for (int nt = 0; nt < NT; ++nt) {
      const int n = wn * WTN + nt * 16 + mn15;
      const int cc = (kgrp + n + (n >> 2)) & 3;
      bfr[0][nt] = *(const s8v*)&sW[0][n * 32 + cc * 8];
      bfr[1][nt] = *(const s8v*)&sW[1][n * 32 + cc * 8];
    }
#pragma unroll
    for (int mt = 0; mt < 4; ++mt)
#pragma unroll
      for (int nt = 0; nt < NT; ++nt) {
        acc[mt][nt] = __builtin_amdgcn_mfma_f32_16x16x32_bf16(af[0][mt], bfr[0][nt], acc[mt][nt], 0, 0, 0);
        acc[mt][nt] = __builtin_amdgcn_mfma_f32_16x16x32_bf16(af[0][mt], bfr[1][nt], acc[mt][nt], 0, 0, 0);
        acc[mt][nt] = __builtin_amdgcn_mfma_f32_16x16x32_bf16(af[1][mt], bfr[0][nt], acc[mt][nt], 0, 0, 0);
      }
    __syncthreads();
  }

  float bv[NT];
#pragma unroll
  for (int nt = 0; nt < NT; ++nt) bv[nt] = bias[bn0 + wn * WTN + nt * 16 + mn15];

  if (POOL == 0) {
#pragma unroll
    for (int mt = 0; mt < 4; ++mt)
#pragma unroll
      for (int nt = 0; nt < NT; ++nt) {
        const int n = bn0 + wn * WTN + nt * 16 + mn15;
#pragma unroll
        for (int r = 0; r < 4; ++r) {
          const size_t m = bm0 + wm * 64 + mt * 16 + (lane >> 4) * 4 + r;
          float v = fmaxf(acc[mt][nt][r] + bv[nt], 0.f);
          unsigned short h, l; bsplit(v, h, l);
          Ch[m * Ndim + n] = h;
          Cl[m * Ndim + n] = l;
        }
      }
  } else if (POOL == 32) {
#pragma unroll
    for (int gq = 0; gq < 2; ++gq)
#pragma unroll
      for (int nt = 0; nt < NT; ++nt) {
        float v = -1e30f;
#pragma unroll
        for (int mt = 2 * gq; mt < 2 * gq + 2; ++mt)
#pragma unroll
          for (int r = 0; r < 4; ++r) v = fmaxf(v, acc[mt][nt][r]);
        v = fmaxf(v + bv[nt], 0.f);
        v = fmaxf(v, __shfl_xor(v, 16, 64));
        v = fmaxf(v, __shfl_xor(v, 32, 64));
        if (lane < 16) {
          const int n = bn0 + wn * WTN + nt * 16 + mn15;
          const size_t row = bm0 / 32 + wm * 2 + gq;
          if (Chp) { unsigned short h, l; bsplit(v, h, l);
                     Chp[row * Ndim + n] = h; Clp[row * Ndim + n] = l; }
          if (Cf) Cf[row * Ndim + n] = v;
        }
      }
  } else if (POOL == 64) {
#pragma unroll
    for (int nt = 0; nt < NT; ++nt) {
      float v = -1e30f;
#pragma unroll
      for (int mt = 0; mt < 4; ++mt)
#pragma unroll
        for (int r = 0; r < 4; ++r) v = fmaxf(v, acc[mt][nt][r]);
      v = fmaxf(v + bv[nt], 0.f);
      v = fmaxf(v, __shfl_xor(v, 16, 64));
      v = fmaxf(v, __shfl_xor(v, 32, 64));
      if (lane < 16) {
        const int n = bn0 + wn * WTN + nt * 16 + mn15;
        const size_t row = bm0 / 64 + wm;
        if (Chp) { unsigned short h, l; bsplit(v, h, l);
                   Chp[row * Ndim + n] = h; Clp[row * Ndim + n] = l; }
        if (Cf) Cf[row * Ndim + n] = v;
      }
    }
  } else {  // POOL == 128
    float part[NT];
#pragma unroll
    for (int nt = 0; nt < NT; ++nt) {
      float v = -1e30f;
#pragma unroll
      for (int mt = 0; mt < 4; ++mt)
#pragma unroll
        for (int r = 0; r < 4; ++r) v = fmaxf(v, acc[mt][nt][r]);
      v = fmaxf(v + bv[nt], 0.f);
      v = fmaxf(v, __shfl_xor(v, 16, 64));
      v = fmaxf(v, __shfl_xor(v, 32, 64));
      part[nt] = v;
      if (lane < 16) sPool[wid][nt * 16 + mn15] = v;
    }
    __syncthreads();
    if (wm == 0 && lane < 16) {
#pragma unroll
      for (int nt = 0; nt < NT; ++nt) {
        float v = fmaxf(part[nt], sPool[wid + 1][nt * 16 + mn15]);
        const int n = bn0 + wn * WTN + nt * 16 + mn15;
        if (Cf) Cf[(size_t)(bm0 / 128) * Ndim + n] = v;
      }
    }
  }
}

// --------------------- skinny GEMV (Mdim == 32) -----------------------
template<bool RELU>
__global__ void gemv_kernel(
    const float* __restrict__ A, const float* __restrict__ W,
    const float* __restrict__ bias, float* __restrict__ C,
    int Mdim, int Ndim, int Kdim)
{
  int o = blockIdx.x * blockDim.x + threadIdx.x;
  if (o >= Mdim * Ndim) return;
  int m = o & 31;
  int n = o >> 5;
  const float4* a4 = (const float4*)(A + (size_t)m * Kdim);
  const float4* w4 = (const float4*)(W + (size_t)n * Kdim);
  float acc = 0.f;
  for (int k = 0; k < (Kdim >> 2); ++k) {
    float4 a = a4[k], w = w4[k];
    acc += a.x * w.x + a.y * w.y + a.z * w.z + a.w * w.w;
  }
  float v = acc + bias[n];
  if (RELU) v = fmaxf(v, 0.f);
  C[(size_t)m * Ndim + n] = v;
}

// =====================================================================
extern "C" void kernel_launch(void* const* d_in, const int* in_sizes, int n_in,
                              void* d_out, int out_size, void* d_ws, size_t ws_size,
                              hipStream_t stream)
{
  (void)in_sizes; (void)n_in; (void)out_size; (void)ws_size;

  const float* points  = (const float*)d_in[0];
  const float* sa1_w[3] = {(const float*)d_in[1], (const float*)d_in[3], (const float*)d_in[5]};
  const float* sa1_b[3] = {(const float*)d_in[2], (const float*)d_in[4], (const float*)d_in[6]};
  const float* sa2_w[3] = {(const float*)d_in[7], (const float*)d_in[9], (const float*)d_in[11]};
  const float* sa2_b[3] = {(const float*)d_in[8], (const float*)d_in[10], (const float*)d_in[12]};
  const float* loc_w[3] = {(const float*)d_in[13], (const float*)d_in[15], (const float*)d_in[17]};
  const float* loc_b[3] = {(const float*)d_in[14], (const float*)d_in[16], (const float*)d_in[18]};
  const float* glob_w0 = (const float*)d_in[19];
  const float* glob_b0 = (const float*)d_in[20];
  const float* glob_w1 = (const float*)d_in[21];
  const float* glob_b1 = (const float*)d_in[22];
  const float* cls_w   = (const float*)d_in[23];
  const float* cls_b   = (const float*)d_in[24];

  char* base = (char*)d_ws;
  size_t off = 0;
  auto alloc = [&](size_t nbytes) -> void* {
    void* p = base + off;
    off += (nbytes + 255) & ~(size_t)255;
    return p;
  };

  // plane ping-pong buffers (bf16 bits as ushort)
  const size_t XE = (size_t)65536 * 160;   // covers SA1 X (131072*64) too
  const size_t YE = (size_t)131072 * 64;
  unsigned short* Xh = (unsigned short*)alloc(XE * 2);
  unsigned short* Xl = (unsigned short*)alloc(XE * 2);
  unsigned short* Yh = (unsigned short*)alloc(YE * 2);
  unsigned short* Yl = (unsigned short*)alloc(YE * 2);
  unsigned short* f1h = (unsigned short*)alloc((size_t)16384 * 128 * 2);
  unsigned short* f1l = (unsigned short*)alloc((size_t)16384 * 128 * 2);
  unsigned short* f2h = (unsigned short*)alloc((size_t)4096 * 256 * 2);
  unsigned short* f2l = (unsigned short*)alloc((size_t)4096 * 256 * 2);

  // weight planes (9 segments, padded K; slot 0 converted but unused)
  const int  wrows[9] = {64, 64, 128, 128, 128, 256, 256, 512, 1024};
  const int  wK[9]    = {3, 64, 64, 131, 128, 128, 256, 256, 512};
  const int  wKP[9]   = {32, 64, 64, 160, 128, 128, 256, 256, 512};
  const float* wsrc[9] = {sa1_w[0], sa1_w[1], sa1_w[2],
                          sa2_w[0], sa2_w[1], sa2_w[2],
                          loc_w[0], loc_w[1], loc_w[2]};
  unsigned short *wph[9], *wpl[9];
  WSplitArgs wa;
  int cum = 0;
  for (int s = 0; s < 9; ++s) {
    size_t e = (size_t)wrows[s] * wKP[s];
    wph[s] = (unsigned short*)alloc(e * 2);
    wpl[s] = (unsigned short*)alloc(e * 2);
    wa.src[s] = wsrc[s]; wa.h[s] = wph[s]; wa.l[s] = wpl[s];
    wa.K[s] = wK[s]; wa.KP[s] = wKP[s]; wa.cum[s] = cum;
    cum += wrows[s] * wKP[s];
  }
  wa.cum[9] = cum;

  float* nx1_aos = (float*)alloc((size_t)32 * 512 * 3 * 4);
  float* nx1_soa = (float*)alloc((size_t)32 * 512 * 3 * 4);
  int*   cidx1   = (int*)  alloc((size_t)32 * 512 * 4);
  int*   idx1    = (int*)  alloc((size_t)32 * 512 * 32 * 4);
  float* nx2_aos = (float*)alloc((size_t)32 * 128 * 3 * 4);
  float* nx2_soa = (float*)alloc((size_t)32 * 128 * 3 * 4);
  int*   cidx2   = (int*)  alloc((size_t)32 * 128 * 4);
  int*   idx2    = (int*)  alloc((size_t)32 * 128 * 64 * 4);
  float* pooled  = (float*)alloc((size_t)32 * 1024 * 4);
  float* gbuf1   = (float*)alloc((size_t)32 * 512 * 4);
  float* gbuf2   = (float*)alloc((size_t)32 * 256 * 4);

  const float r2a = (float)(0.2 * 0.2);
  const float r2b = (float)(0.4 * 0.4);

  wsplit_all<<<CDIV(cum, 256), 256, 0, stream>>>(wa);

  // ---------------- SA1 ----------------
  fps_kernel<8192, 512, 512><<<32, 512, 0, stream>>>(points, 24576, 8192, cidx1);
  gatherc_kernel<<<32, 512, 0, stream>>>(points, 24576, 8192, cidx1, 512, nx1_aos, nx1_soa);
  ballq_wave<8192, 32, 512><<<32 * 512, 64, 0, stream>>>(points, 24576, 8192, nx1_aos, idx1, r2a);

  for (int c = 0; c < 4; ++c) {
    const int g0 = c * 4096;
    const int rows = 4096 * 32;  // 131072
    sa1l1_kernel<<<CDIV(rows, 64), 256, 0, stream>>>(
        points, idx1, nx1_aos, sa1_w[0], sa1_b[0], Yh, Yl, g0, rows);
    mfma_gemm<64, 0><<<dim3(1, rows / 128), 256, 0, stream>>>(
        Yh, Yl, wph[1], wpl[1], sa1_b[1], Xh, Xl, nullptr, nullptr, nullptr, 64, 64);
    mfma_gemm<128, 32><<<dim3(1, rows / 128), 256, 0, stream>>>(
        Xh, Xl, wph[2], wpl[2], sa1_b[2], nullptr, nullptr, nullptr,
        f1h + (size_t)g0 * 128, f1l + (size_t)g0 * 128, 64, 128);
  }

  // ---------------- SA2 ----------------
  fps_kernel<512, 128, 256><<<32, 256, 0, stream>>>(nx1_soa, 1536, 512, cidx2);
  gatherc_kernel<<<32, 128, 0, stream>>>(nx1_soa, 1536, 512, cidx2, 128, nx2_aos, nx2_soa);
  ballq_wave<512, 64, 128><<<32 * 128, 64, 0, stream>>>(nx1_soa, 1536, 512, nx2_aos, idx2, r2b);

  for (int c = 0; c < 4; ++c) {
    const int g0 = c * 1024;
    const int rows = 1024 * 64;  // 65536
    gather2p_kernel<<<dim3(rows / 4), dim3(64, 4), 0, stream>>>(
        nx1_aos, f1h, f1l, idx2, nx2_aos, Xh, Xl, g0);
    mfma_gemm<128, 0><<<dim3(1, rows / 128), 256, 0, stream>>>(
        Xh, Xl, wph[3], wpl[3], sa2_b[0], Yh, Yl, nullptr, nullptr, nullptr, 160, 128);
    mfma_gemm<128, 0><<<dim3(1, rows / 128), 256, 0, stream>>>(
        Yh, Yl, wph[4], wpl[4], sa2_b[1], Xh, Xl, nullptr, nullptr, nullptr, 128, 128);
    mfma_gemm<128, 64><<<dim3(2, rows / 128), 256, 0, stream>>>(
        Xh, Xl, wph[5], wpl[5], sa2_b[2], nullptr, nullptr, nullptr,
        f2h + (size_t)g0 * 256, f2l + (size_t)g0 * 256, 128, 256);
  }

  // ---------------- loc MLP (fused global maxpool at L3) ----------------
  mfma_gemm<128, 0><<<dim3(2, 32), 256, 0, stream>>>(
      f2h, f2l, wph[6], wpl[6], loc_b[0], Yh, Yl, nullptr, nullptr, nullptr, 256, 256);
  mfma_gemm<128, 0><<<dim3(4, 32), 256, 0, stream>>>(
      Yh, Yl, wph[7], wpl[7], loc_b[1], Xh, Xl, nullptr, nullptr, nullptr, 256, 512);
  mfma_gemm<128, 128><<<dim3(8, 32), 256, 0, stream>>>(
      Xh, Xl, wph[8], wpl[8], loc_b[2], nullptr, nullptr, pooled, nullptr, nullptr, 512, 1024);

  // ---------------- glob MLP + classifier ----------------
  gemv_kernel<true><<<CDIV(32 * 512, 256), 256, 0, stream>>>(pooled, glob_w0, glob_b0, gbuf1, 32, 512, 1024);
  gemv_kernel<true><<<CDIV(32 * 256, 256), 256, 0, stream>>>(gbuf1, glob_w1, glob_b1, gbuf2, 32, 256, 512);
  gemv_kernel<false><<<CDIV(32 * 40, 256), 256, 0, stream>>>(gbuf2, cls_w, cls_b, (float*)d_out, 32, 40, 256);
}

// Round 4
// 1431.588 us; speedup vs baseline: 2.7302x; 1.0354x over previous
//
#include <hip/hip_runtime.h>
#include <hip/hip_bf16.h>
#include <cstdint>

#define CDIV(a,b) (((a)+(b)-1)/(b))

typedef short s8v __attribute__((ext_vector_type(8)));
typedef float f4v __attribute__((ext_vector_type(4)));

// ---------------------------------------------------------------------
// helpers
// ---------------------------------------------------------------------
__device__ __forceinline__ unsigned short f2bf_bits(float v) {
  __hip_bfloat16 b = __float2bfloat16(v);
  unsigned short u; __builtin_memcpy(&u, &b, 2);
  return u;
}
__device__ __forceinline__ void bsplit(float v, unsigned short& h, unsigned short& l) {
  __hip_bfloat16 hb = __float2bfloat16(v);
  float hf = __bfloat162float(hb);
  unsigned short hu; __builtin_memcpy(&hu, &hb, 2);
  h = hu;
  l = f2bf_bits(v - hf);
}

// async global->LDS, 16B per lane; lds base must be wave-uniform.
__device__ __forceinline__ void gl2lds16(const void* g, void* l, int lane) {
#if __has_builtin(__builtin_amdgcn_global_load_lds)
  __builtin_amdgcn_global_load_lds(
      (const __attribute__((address_space(1))) unsigned int*)g,
      (__attribute__((address_space(3))) unsigned int*)l, 16, 0, 0);
#else
  ((uint4*)l)[lane] = *(const uint4*)g;
#endif
}

// ---------------------------------------------------------------------
// FPS — DPP wave argmax with coords carried; block combine via broadcast
// LDS reads (5 LDS instr/wave/iter instead of 16). 1 barrier/iter.
// ---------------------------------------------------------------------
template<int C>
__device__ __forceinline__ unsigned dpp32(unsigned v) {
  return (unsigned)__builtin_amdgcn_update_dpp((int)v, (int)v, C, 0xF, 0xF, false);
}
template<int C>
__device__ __forceinline__ void red_step(unsigned long long& pk, float& x, float& y, float& z) {
  unsigned lo = dpp32<C>((unsigned)pk);
  unsigned hi = dpp32<C>((unsigned)(pk >> 32));
  unsigned long long p2 = ((unsigned long long)hi << 32) | lo;
  float x2 = __uint_as_float(dpp32<C>(__float_as_uint(x)));
  float y2 = __uint_as_float(dpp32<C>(__float_as_uint(y)));
  float z2 = __uint_as_float(dpp32<C>(__float_as_uint(z)));
  if (p2 > pk) { pk = p2; x = x2; y = y2; z = z2; }
}

template<int NPTS, int MOUT, int NTHR>
__global__ __launch_bounds__(NTHR, 1) void fps_kernel(
    const float* __restrict__ pts, int bstride, int cstride,
    int* __restrict__ out_idx)
{
  constexpr int PPT = NPTS / NTHR;
  constexpr int NW  = NTHR / 64;
  const int b = blockIdx.x, t = threadIdx.x;
  const int lane = t & 63, wid = t >> 6;
  const float* px = pts + (size_t)b * bstride;
  const float* py = px + cstride;
  const float* pz = px + 2 * cstride;
  __shared__ __align__(16) unsigned long long s_key[2][NW];
  __shared__ __align__(16) float4 s_c4[2][NW];

  float xs[PPT], ys[PPT], zs[PPT], ds[PPT];
#pragma unroll
  for (int j = 0; j < PPT; ++j) {
    int i = t + j * NTHR;
    xs[j] = px[i]; ys[j] = py[i]; zs[j] = pz[i];
    ds[j] = 1e10f;
  }
  if (t == 0) out_idx[(size_t)b * MOUT] = 0;
  float lx = px[0], ly = py[0], lz = pz[0];

  for (int it = 1; it < MOUT; ++it) {
    const int pb = it & 1;
    float bestv = -1.0f; int besti = 0;
    float bx = 0.f, by = 0.f, bz = 0.f;
#pragma unroll
    for (int j = 0; j < PPT; ++j) {
      float dx = xs[j] - lx, dy = ys[j] - ly, dz = zs[j] - lz;
      float d  = dx * dx + dy * dy + dz * dz;
      float nd = fminf(ds[j], d);
      ds[j] = nd;
      if (nd > bestv) { bestv = nd; besti = t + j * NTHR; bx = xs[j]; by = ys[j]; bz = zs[j]; }
    }
    unsigned long long pk =
        ((unsigned long long)__float_as_uint(bestv) << 32) | (unsigned)(~(unsigned)besti);
    red_step<0x111>(pk, bx, by, bz);   // row_shr:1
    red_step<0x112>(pk, bx, by, bz);   // row_shr:2
    red_step<0x114>(pk, bx, by, bz);   // row_shr:4
    red_step<0x118>(pk, bx, by, bz);   // row_shr:8
    red_step<0x142>(pk, bx, by, bz);   // row_bcast:15
    red_step<0x143>(pk, bx, by, bz);   // row_bcast:31 -> lane 63 has wave winner
    if (lane == 63) {
      s_key[pb][wid] = pk;
      s_c4[pb][wid] = make_float4(bx, by, bz, 0.f);
    }
    __syncthreads();
    // broadcast-read all NW keys (b128 pairs), register compare tree
    unsigned long long kk[NW];
    const ulonglong2* kp = (const ulonglong2*)&s_key[pb][0];
#pragma unroll
    for (int q = 0; q < NW / 2; ++q) { ulonglong2 v = kp[q]; kk[2 * q] = v.x; kk[2 * q + 1] = v.y; }
    unsigned long long kbest = kk[0];
#pragma unroll
    for (int q = 1; q < NW; ++q) if (kk[q] > kbest) kbest = kk[q];
    const int widx = (int)(~(unsigned)kbest);
    const int wwin = (widx & (NTHR - 1)) >> 6;
    float4 c4 = s_c4[pb][wwin];      // same addr across lanes -> broadcast
    lx = c4.x; ly = c4.y; lz = c4.z;
    if (t == 0) out_idx[(size_t)b * MOUT + it] = widx;
  }
}

// -------------------- centroid gather (AoS + SoA) ---------------------
__global__ void gatherc_kernel(
    const float* __restrict__ pts, int bstride, int cstride,
    const int* __restrict__ cidx, int M,
    float* __restrict__ aos, float* __restrict__ soa)
{
  const int b = blockIdx.x, t = threadIdx.x;  // blockDim == M
  const int i = cidx[(size_t)b * M + t];
  const float* p = pts + (size_t)b * bstride;
  float x = p[i], y = p[cstride + i], z = p[2 * cstride + i];
  size_t g = (size_t)b * M + t;
  aos[g * 3 + 0] = x; aos[g * 3 + 1] = y; aos[g * 3 + 2] = z;
  soa[(size_t)b * 3 * M + t]         = x;
  soa[(size_t)b * 3 * M + M + t]     = y;
  soa[(size_t)b * 3 * M + 2 * M + t] = z;
}

// ---------------- ball query — one wave per centroid ------------------
// Rolling depth-1 prefetch of the next chunk hides L2 latency.
template<int NPTS, int KNB, int MC>
__global__ __launch_bounds__(64) void ballq_wave(
    const float* __restrict__ pts, int bstride, int cstride,
    const float* __restrict__ cents, int* __restrict__ out, float r2)
{
  constexpr int NCH = NPTS / 64;
  const int g = blockIdx.x;
  const int b = g / MC;
  const int lane = threadIdx.x;
  const float* px = pts + (size_t)b * bstride;
  const float* py = px + cstride;
  const float* pz = px + 2 * cstride;
  const float cx = cents[g * 3 + 0], cy = cents[g * 3 + 1], cz = cents[g * 3 + 2];
  __shared__ int s_idx[KNB];
  float nx = px[lane], ny = py[lane], nz = pz[lane];
  int base = 0;
  for (int c = 0; c < NCH; ++c) {
    float X = nx, Y = ny, Z = nz;
    if (c + 1 < NCH) {
      int i2 = (c + 1) * 64 + lane;
      nx = px[i2]; ny = py[i2]; nz = pz[i2];
    }
    float dx = X - cx, dy = Y - cy, dz = Z - cz;
    bool valid = (dx * dx + dy * dy + dz * dz) < r2;
    unsigned long long mask = __ballot(valid);
    int rank = __popcll(mask & ((1ull << lane) - 1ull));
    int pos = base + rank;
    if (valid && pos < KNB) s_idx[pos] = c * 64 + lane;
    base += __popcll(mask);
    if (base >= KNB) break;   // wave-uniform
  }
  int total = base < KNB ? base : KNB;   // >=1 (centroid hits itself)
  int first = s_idx[0];
  if (lane < KNB)
    out[(size_t)g * KNB + lane] = (lane < total) ? s_idx[lane] : first;
}

// ----------- fused SA1 gather + layer1 (K=3, exact fp32 VALU) ----------
__global__ __launch_bounds__(256) void sa1l1_kernel(
    const float* __restrict__ pts, const int* __restrict__ idx1,
    const float* __restrict__ cents,
    const float* __restrict__ w0, const float* __restrict__ b0,
    unsigned short* __restrict__ Yh, unsigned short* __restrict__ Yl,
    int g0, int nrows)
{
  __shared__ float sw[192];
  __shared__ float sb[64];
  const int tid = threadIdx.x;
  if (tid < 192) sw[tid] = w0[tid];
  else sb[tid - 192] = b0[tid - 192];
  __syncthreads();
  const int r = blockIdx.x * 64 + (tid >> 2);
  if (r >= nrows) return;
  const int q = tid & 3;
  const int gl = r >> 5, j = r & 31, gg = g0 + gl, b = gg >> 9;
  const int i = idx1[(size_t)gg * 32 + j];
  const float* px = pts + (size_t)b * 24576;
  const float x = px[i]         - cents[gg * 3 + 0];
  const float y = px[8192 + i]  - cents[gg * 3 + 1];
  const float z = px[16384 + i] - cents[gg * 3 + 2];
  union { unsigned short us[16]; uint4 v[2]; } ph, pl;
#pragma unroll
  for (int u = 0; u < 16; ++u) {
    const int o = q * 16 + u;
    float v = sw[o * 3] * x + sw[o * 3 + 1] * y + sw[o * 3 + 2] * z + sb[o];
    v = fmaxf(v, 0.f);
    bsplit(v, ph.us[u], pl.us[u]);
  }
  uint4* dh = (uint4*)(Yh + (size_t)r * 64 + q * 16);
  uint4* dl = (uint4*)(Yl + (size_t)r * 64 + q * 16);
  dh[0] = ph.v[0]; dh[1] = ph.v[1];
  dl[0] = pl.v[0]; dl[1] = pl.v[1];
}

// -------- gather2 -> planes, width 160, PERMUTED: [feats(128)|xyz(3)|pad] ---
// feats copied as uint4; one wave handles one row (h-plane lanes 0..19,
// l-plane lanes 32..51).
__global__ void gather2p_kernel(
    const float* __restrict__ nx1_aos,
    const unsigned short* __restrict__ f1h, const unsigned short* __restrict__ f1l,
    const int* __restrict__ idx2, const float* __restrict__ nx2_aos,
    unsigned short* __restrict__ Xh, unsigned short* __restrict__ Xl, int g0)
{
  const int r = blockIdx.x * 4 + threadIdx.y;   // blockDim (64,4)
  const int lane = threadIdx.x;
  int gl = r >> 6, j = r & 63;
  int gg = g0 + gl;
  int b  = gg >> 7;
  int i  = idx2[(size_t)gg * 64 + j];
  int p  = b * 512 + i;
  size_t ro = (size_t)r * 160;
  const int slot = lane & 31;
  const bool isL = lane >= 32;
  unsigned short* dst = isL ? Xl : Xh;
  const unsigned short* f1 = isL ? f1l : f1h;
  if (slot < 16) {
    ((uint4*)(dst + ro))[slot] = ((const uint4*)(f1 + (size_t)p * 128))[slot];
  } else if (slot == 16) {
    union { unsigned short us[8]; uint4 v; } pk;
#pragma unroll
    for (int u = 0; u < 8; ++u) pk.us[u] = 0;
#pragma unroll
    for (int c = 0; c < 3; ++c) {
      float v = nx1_aos[(size_t)p * 3 + c] - nx2_aos[(size_t)gg * 3 + c];
      unsigned short h, l; bsplit(v, h, l);
      pk.us[c] = isL ? l : h;
    }
    ((uint4*)(dst + ro))[16] = pk.v;
  } else if (slot <= 19) {
    ((uint4*)(dst + ro))[slot] = make_uint4(0, 0, 0, 0);
  }
}

// ------------- all weight fp32 -> hi/lo splits in ONE launch -----------
// perm==1 (sa2_w0): output col c -> src col (c<128 ? c+3 : c<131 ? c-128 : pad)
struct WSplitArgs {
  const float* src[9];
  unsigned short* h[9];
  unsigned short* l[9];
  int K[9];
  int KP[9];
  int perm[9];
  int cum[10];
};
__global__ void wsplit_all(WSplitArgs a) {
  int i = blockIdx.x * 256 + threadIdx.x;
  if (i >= a.cum[9]) return;
  int s = 0;
#pragma unroll
  for (int t = 1; t < 9; ++t) s += (i >= a.cum[t]);
  int local = i - a.cum[s];
  int KP = a.KP[s], K = a.K[s];
  int r = local / KP, k = local - r * KP;
  int oc;
  if (a.perm[s]) oc = (k < 128) ? k + 3 : (k < 131 ? k - 128 : -1);
  else           oc = (k < K) ? k : -1;
  float v = (oc >= 0) ? a.src[s][(size_t)r * K + oc] : 0.f;
  unsigned short hb, lb; bsplit(v, hb, lb);
  a.h[s][local] = hb; a.l[s][local] = lb;
}

// ---------------------------------------------------------------------
// MFMA GEMM: C[M,N] = relu(A[M,K] @ W[N,K]^T + b), 3-term bf16 split.
// POOL=0: write hi/lo planes Ch/Cl. POOL=32/64/128: fused row max-pool.
// ---------------------------------------------------------------------
template<int BN, int POOL>
__global__ __launch_bounds__(256, 1) void mfma_gemm(
    const unsigned short* __restrict__ Ah, const unsigned short* __restrict__ Al,
    const unsigned short* __restrict__ Wh, const unsigned short* __restrict__ Wl,
    const float* __restrict__ bias,
    unsigned short* __restrict__ Ch, unsigned short* __restrict__ Cl,
    float* __restrict__ Cf,
    unsigned short* __restrict__ Chp, unsigned short* __restrict__ Clp,
    int Kdim, int Ndim)
{
  constexpr int WTN = BN / 2, NT = WTN / 16;
  __shared__ unsigned short sA[2][128 * 32];
  __shared__ unsigned short sW[2][BN * 32];
  __shared__ float sPool[4][WTN];
  const int tid = threadIdx.x, lane = tid & 63, wid = tid >> 6;
  const int wm = wid & 1, wn = wid >> 1;
  const size_t bm0 = (size_t)blockIdx.y * 128;
  const int bn0 = blockIdx.x * BN;
  const int mn15 = lane & 15, kgrp = lane >> 4;

  f4v acc[4][NT];
#pragma unroll
  for (int a = 0; a < 4; ++a)
#pragma unroll
    for (int b = 0; b < NT; ++b) acc[a][b] = (f4v){0.f, 0.f, 0.f, 0.f};

  const int sc = lane & 3, srl = lane >> 2;

  for (int k0 = 0; k0 < Kdim; k0 += 32) {
#pragma unroll
    for (int hh = 0; hh < 2; ++hh) {
      const int R = wid * 32 + hh * 16;
      const int m = R + srl;
      const int kg = (sc - m - (m >> 2)) & 3;
      const size_t go = (bm0 + m) * (size_t)Kdim + k0 + kg * 8;
      gl2lds16(Ah + go, &sA[0][R * 32], lane);
      gl2lds16(Al + go, &sA[1][R * 32], lane);
    }
    if (BN == 128) {
#pragma unroll
      for (int hh = 0; hh < 2; ++hh) {
        const int R = wid * 32 + hh * 16;
        const int n = R + srl;
        const int kg = (sc - n - (n >> 2)) & 3;
        const size_t go = (size_t)(bn0 + n) * Kdim + k0 + kg * 8;
        gl2lds16(Wh + go, &sW[0][R * 32], lane);
        gl2lds16(Wl + go, &sW[1][R * 32], lane);
      }
    } else {
      const int R = wid * 16;
      const int n = R + srl;
      const int kg = (sc - n - (n >> 2)) & 3;
      const size_t go = (size_t)(bn0 + n) * Kdim + k0 + kg * 8;
      gl2lds16(Wh + go, &sW[0][R * 32], lane);
      gl2lds16(Wl + go, &sW[1][R * 32], lane);
    }
    __syncthreads();

    s8v af[2][4], bfr[2][NT];
#pragma unroll
    for (int mt = 0; mt < 4; ++mt) {
      const int m = wm * 64 + mt * 16 + mn15;
      const int cc = (kgrp + m + (m >> 2)) & 3;
      af[0][mt] = *(const s8v*)&sA[0][m * 32 + cc * 8];
      af[1][mt] = *(const s8v*)&sA[1][m * 32 + cc * 8];
    }
#pragma unroll
    for (int nt = 0; nt < NT; ++nt) {
      const int n = wn * WTN + nt * 16 + mn15;
      const int cc = (kgrp + n + (n >> 2)) & 3;
      bfr[0][nt] = *(const s8v*)&sW[0][n * 32 + cc * 8];
      bfr[1][nt] = *(const s8v*)&sW[1][n * 32 + cc * 8];
    }
#pragma unroll
    for (int mt = 0; mt < 4; ++mt)
#pragma unroll
      for (int nt = 0; nt < NT; ++nt) {
        acc[mt][nt] = __builtin_amdgcn_mfma_f32_16x16x32_bf16(af[0][mt], bfr[0][nt], acc[mt][nt], 0, 0, 0);
        acc[mt][nt] = __builtin_amdgcn_mfma_f32_16x16x32_bf16(af[0][mt], bfr[1][nt], acc[mt][nt], 0, 0, 0);
        acc[mt][nt] = __builtin_amdgcn_mfma_f32_16x16x32_bf16(af[1][mt], bfr[0][nt], acc[mt][nt], 0, 0, 0);
      }
    __syncthreads();
  }

  float bv[NT];
#pragma unroll
  for (int nt = 0; nt < NT; ++nt) bv[nt] = bias[bn0 + wn * WTN + nt * 16 + mn15];

  if (POOL == 0) {
#pragma unroll
    for (int mt = 0; mt < 4; ++mt)
#pragma unroll
      for (int nt = 0; nt < NT; ++nt) {
        const int n = bn0 + wn * WTN + nt * 16 + mn15;
#pragma unroll
        for (int r = 0; r < 4; ++r) {
          const size_t m = bm0 + wm * 64 + mt * 16 + (lane >> 4) * 4 + r;
          float v = fmaxf(acc[mt][nt][r] + bv[nt], 0.f);
          unsigned short h, l; bsplit(v, h, l);
          Ch[m * Ndim + n] = h;
          Cl[m * Ndim + n] = l;
        }
      }
  } else if (POOL == 32) {
#pragma unroll
    for (int gq = 0; gq < 2; ++gq)
#pragma unroll
      for (int nt = 0; nt < NT; ++nt) {
        float v = -1e30f;
#pragma unroll
        for (int mt = 2 * gq; mt < 2 * gq + 2; ++mt)
#pragma unroll
          for (int r = 0; r < 4; ++r) v = fmaxf(v, acc[mt][nt][r]);
        v = fmaxf(v + bv[nt], 0.f);
        v = fmaxf(v, __shfl_xor(v, 16, 64));
        v = fmaxf(v, __shfl_xor(v, 32, 64));
        if (lane < 16) {
          const int n = bn0 + wn * WTN + nt * 16 + mn15;
          const size_t row = bm0 / 32 + wm * 2 + gq;
          if (Chp) { unsigned short h, l; bsplit(v, h, l);
                     Chp[row * Ndim + n] = h; Clp[row * Ndim + n] = l; }
          if (Cf) Cf[row * Ndim + n] = v;
        }
      }
  } else if (POOL == 64) {
#pragma unroll
    for (int nt = 0; nt < NT; ++nt) {
      float v = -1e30f;
#pragma unroll
      for (int mt = 0; mt < 4; ++mt)
#pragma unroll
        for (int r = 0; r < 4; ++r) v = fmaxf(v, acc[mt][nt][r]);
      v = fmaxf(v + bv[nt], 0.f);
      v = fmaxf(v, __shfl_xor(v, 16, 64));
      v = fmaxf(v, __shfl_xor(v, 32, 64));
      if (lane < 16) {
        const int n = bn0 + wn * WTN + nt * 16 + mn15;
        const size_t row = bm0 / 64 + wm;
        if (Chp) { unsigned short h, l; bsplit(v, h, l);
                   Chp[row * Ndim + n] = h; Clp[row * Ndim + n] = l; }
        if (Cf) Cf[row * Ndim + n] = v;
      }
    }
  } else {  // POOL == 128
    float part[NT];
#pragma unroll
    for (int nt = 0; nt < NT; ++nt) {
      float v = -1e30f;
#pragma unroll
      for (int mt = 0; mt < 4; ++mt)
#pragma unroll
        for (int r = 0; r < 4; ++r) v = fmaxf(v, acc[mt][nt][r]);
      v = fmaxf(v + bv[nt], 0.f);
      v = fmaxf(v, __shfl_xor(v, 16, 64));
      v = fmaxf(v, __shfl_xor(v, 32, 64));
      part[nt] = v;
      if (lane < 16) sPool[wid][nt * 16 + mn15] = v;
    }
    __syncthreads();
    if (wm == 0 && lane < 16) {
#pragma unroll
      for (int nt = 0; nt < NT; ++nt) {
        float v = fmaxf(part[nt], sPool[wid + 1][nt * 16 + mn15]);
        const int n = bn0 + wn * WTN + nt * 16 + mn15;
        if (Cf) Cf[(size_t)(bm0 / 128) * Ndim + n] = v;
      }
    }
  }
}

// ------------- fused head: glob0 -> glob1 -> cls, 1 block/batch --------
__global__ __launch_bounds__(256) void head_kernel(
    const float* __restrict__ pooled,
    const float* __restrict__ w0, const float* __restrict__ b0,
    const float* __restrict__ w1, const float* __restrict__ b1,
    const float* __restrict__ wc, const float* __restrict__ bc,
    float* __restrict__ out)
{
  __shared__ float sx[1024];
  __shared__ float sy[512];
  __shared__ float sz[256];
  const int b = blockIdx.x, t = threadIdx.x;
  for (int i = t; i < 1024; i += 256) sx[i] = pooled[(size_t)b * 1024 + i];
  __syncthreads();
  for (int o = t; o < 512; o += 256) {
    const float4* w4 = (const float4*)(w0 + (size_t)o * 1024);
    const float4* x4 = (const float4*)sx;
    float acc = 0.f;
#pragma unroll 4
    for (int k = 0; k < 256; ++k) {
      float4 w = w4[k], x = x4[k];
      acc += w.x * x.x + w.y * x.y + w.z * x.z + w.w * x.w;
    }
    sy[o] = fmaxf(acc + b0[o], 0.f);
  }
  __syncthreads();
  if (t < 256) {
    const float4* w4 = (const float4*)(w1 + (size_t)t * 512);
    const float4* y4 = (const float4*)sy;
    float acc = 0.f;
#pragma unroll 4
    for (int k = 0; k < 128; ++k) {
      float4 w = w4[k], y = y4[k];
      acc += w.x * y.x + w.y * y.y + w.z * y.z + w.w * y.w;
    }
    sz[t] = fmaxf(acc + b1[t], 0.f);
  }
  __syncthreads();
  if (t < 40) {
    const float4* w4 = (const float4*)(wc + (size_t)t * 256);
    const float4* z4 = (const float4*)sz;
    float acc = 0.f;
#pragma unroll 4
    for (int k = 0; k < 64; ++k) {
      float4 w = w4[k], z = z4[k];
      acc += w.x * z.x + w.y * z.y + w.z * z.z + w.w * z.w;
    }
    out[(size_t)b * 40 + t] = acc + bc[t];
  }
}

// =====================================================================
extern "C" void kernel_launch(void* const* d_in, const int* in_sizes, int n_in,
                              void* d_out, int out_size, void* d_ws, size_t ws_size,
                              hipStream_t stream)
{
  (void)in_sizes; (void)n_in; (void)out_size; (void)ws_size;

  const float* points  = (const float*)d_in[0];
  const float* sa1_w[3] = {(const float*)d_in[1], (const float*)d_in[3], (const float*)d_in[5]};
  const float* sa1_b[3] = {(const float*)d_in[2], (const float*)d_in[4], (const float*)d_in[6]};
  const float* sa2_w[3] = {(const float*)d_in[7], (const float*)d_in[9], (const float*)d_in[11]};
  const float* sa2_b[3] = {(const float*)d_in[8], (const float*)d_in[10], (const float*)d_in[12]};
  const float* loc_w[3] = {(const float*)d_in[13], (const float*)d_in[15], (const float*)d_in[17]};
  const float* loc_b[3] = {(const float*)d_in[14], (const float*)d_in[16], (const float*)d_in[18]};
  const float* glob_w0 = (const float*)d_in[19];
  const float* glob_b0 = (const float*)d_in[20];
  const float* glob_w1 = (const float*)d_in[21];
  const float* glob_b1 = (const float*)d_in[22];
  const float* cls_w   = (const float*)d_in[23];
  const float* cls_b   = (const float*)d_in[24];

  char* base = (char*)d_ws;
  size_t off = 0;
  auto alloc = [&](size_t nbytes) -> void* {
    void* p = base + off;
    off += (nbytes + 255) & ~(size_t)255;
    return p;
  };

  // plane ping-pong buffers (bf16 bits as ushort)
  const size_t XE = (size_t)65536 * 160;   // covers SA1 X (131072*64) too
  const size_t YE = (size_t)131072 * 64;
  unsigned short* Xh = (unsigned short*)alloc(XE * 2);
  unsigned short* Xl = (unsigned short*)alloc(XE * 2);
  unsigned short* Yh = (unsigned short*)alloc(YE * 2);
  unsigned short* Yl = (unsigned short*)alloc(YE * 2);
  unsigned short* f1h = (unsigned short*)alloc((size_t)16384 * 128 * 2);
  unsigned short* f1l = (unsigned short*)alloc((size_t)16384 * 128 * 2);
  unsigned short* f2h = (unsigned short*)alloc((size_t)4096 * 256 * 2);
  unsigned short* f2l = (unsigned short*)alloc((size_t)4096 * 256 * 2);

  // weight planes (9 segments, padded K; slot 0 converted but unused)
  const int  wrows[9] = {64, 64, 128, 128, 128, 256, 256, 512, 1024};
  const int  wK[9]    = {3, 64, 64, 131, 128, 128, 256, 256, 512};
  const int  wKP[9]   = {32, 64, 64, 160, 128, 128, 256, 256, 512};
  const float* wsrc[9] = {sa1_w[0], sa1_w[1], sa1_w[2],
                          sa2_w[0], sa2_w[1], sa2_w[2],
                          loc_w[0], loc_w[1], loc_w[2]};
  unsigned short *wph[9], *wpl[9];
  WSplitArgs wa;
  int cum = 0;
  for (int s = 0; s < 9; ++s) {
    size_t e = (size_t)wrows[s] * wKP[s];
    wph[s] = (unsigned short*)alloc(e * 2);
    wpl[s] = (unsigned short*)alloc(e * 2);
    wa.src[s] = wsrc[s]; wa.h[s] = wph[s]; wa.l[s] = wpl[s];
    wa.K[s] = wK[s]; wa.KP[s] = wKP[s]; wa.cum[s] = cum;
    wa.perm[s] = (s == 3) ? 1 : 0;
    cum += wrows[s] * wKP[s];
  }
  wa.cum[9] = cum;

  float* nx1_aos = (float*)alloc((size_t)32 * 512 * 3 * 4);
  float* nx1_soa = (float*)alloc((size_t)32 * 512 * 3 * 4);
  int*   cidx1   = (int*)  alloc((size_t)32 * 512 * 4);
  int*   idx1    = (int*)  alloc((size_t)32 * 512 * 32 * 4);
  float* nx2_aos = (float*)alloc((size_t)32 * 128 * 3 * 4);
  float* nx2_soa = (float*)alloc((size_t)32 * 128 * 3 * 4);
  int*   cidx2   = (int*)  alloc((size_t)32 * 128 * 4);
  int*   idx2    = (int*)  alloc((size_t)32 * 128 * 64 * 4);
  float* pooled  = (float*)alloc((size_t)32 * 1024 * 4);

  const float r2a = (float)(0.2 * 0.2);
  const float r2b = (float)(0.4 * 0.4);

  wsplit_all<<<CDIV(cum, 256), 256, 0, stream>>>(wa);

  // ---------------- SA1 ----------------
  fps_kernel<8192, 512, 512><<<32, 512, 0, stream>>>(points, 24576, 8192, cidx1);
  gatherc_kernel<<<32, 512, 0, stream>>>(points, 24576, 8192, cidx1, 512, nx1_aos, nx1_soa);
  ballq_wave<8192, 32, 512><<<32 * 512, 64, 0, stream>>>(points, 24576, 8192, nx1_aos, idx1, r2a);

  for (int c = 0; c < 4; ++c) {
    const int g0 = c * 4096;
    const int rows = 4096 * 32;  // 131072
    sa1l1_kernel<<<CDIV(rows, 64), 256, 0, stream>>>(
        points, idx1, nx1_aos, sa1_w[0], sa1_b[0], Yh, Yl, g0, rows);
    mfma_gemm<64, 0><<<dim3(1, rows / 128), 256, 0, stream>>>(
        Yh, Yl, wph[1], wpl[1], sa1_b[1], Xh, Xl, nullptr, nullptr, nullptr, 64, 64);
    mfma_gemm<128, 32><<<dim3(1, rows / 128), 256, 0, stream>>>(
        Xh, Xl, wph[2], wpl[2], sa1_b[2], nullptr, nullptr, nullptr,
        f1h + (size_t)g0 * 128, f1l + (size_t)g0 * 128, 64, 128);
  }

  // ---------------- SA2 ----------------
  fps_kernel<512, 128, 256><<<32, 256, 0, stream>>>(nx1_soa, 1536, 512, cidx2);
  gatherc_kernel<<<32, 128, 0, stream>>>(nx1_soa, 1536, 512, cidx2, 128, nx2_aos, nx2_soa);
  ballq_wave<512, 64, 128><<<32 * 128, 64, 0, stream>>>(nx1_soa, 1536, 512, nx2_aos, idx2, r2b);

  for (int c = 0; c < 4; ++c) {
    const int g0 = c * 1024;
    const int rows = 1024 * 64;  // 65536
    gather2p_kernel<<<dim3(rows / 4), dim3(64, 4), 0, stream>>>(
        nx1_aos, f1h, f1l, idx2, nx2_aos, Xh, Xl, g0);
    mfma_gemm<128, 0><<<dim3(1, rows / 128), 256, 0, stream>>>(
        Xh, Xl, wph[3], wpl[3], sa2_b[0], Yh, Yl, nullptr, nullptr, nullptr, 160, 128);
    mfma_gemm<128, 0><<<dim3(1, rows / 128), 256, 0, stream>>>(
        Yh, Yl, wph[4], wpl[4], sa2_b[1], Xh, Xl, nullptr, nullptr, nullptr, 128, 128);
    mfma_gemm<128, 64><<<dim3(2, rows / 128), 256, 0, stream>>>(
        Xh, Xl, wph[5], wpl[5], sa2_b[2], nullptr, nullptr, nullptr,
        f2h + (size_t)g0 * 256, f2l + (size_t)g0 * 256, 128, 256);
  }

  // ---------------- loc MLP (fused global maxpool at L3) ----------------
  mfma_gemm<128, 0><<<dim3(2, 32), 256, 0, stream>>>(
      f2h, f2l, wph[6], wpl[6], loc_b[0], Yh, Yl, nullptr, nullptr, nullptr, 256, 256);
  mfma_gemm<128, 0><<<dim3(4, 32), 256, 0, stream>>>(
      Yh, Yl, wph[7], wpl[7], loc_b[1], Xh, Xl, nullptr, nullptr, nullptr, 256, 512);
  mfma_gemm<128, 128><<<dim3(8, 32), 256, 0, stream>>>(
      Xh, Xl, wph[8], wpl[8], loc_b[2], nullptr, nullptr, pooled, nullptr, nullptr, 512, 1024);

  // ---------------- fused head ----------------
  head_kernel<<<32, 256, 0, stream>>>(pooled, glob_w0, glob_b0,
                                      glob_w1, glob_b1, cls_w, cls_b, (float*)d_out);
}